// Round 7
// baseline (570.077 us; speedup 1.0000x reference)
//
#include <hip/hip_runtime.h>
#include <hip/hip_bf16.h>

#define NN 50000
#define NPAIR 25000     // packed 2x16-bit LDS counters: 25000 u32 = 100KB (<160KB)
#define CSH 13          // hist chunk = 8192 edges/block
#define CHUNK (1 << CSH)

typedef short short8 __attribute__((ext_vector_type(8)));
typedef float f32x4 __attribute__((ext_vector_type(4)));

#define GLOBAL_AS __attribute__((address_space(1)))
#define LDS_AS __attribute__((address_space(3)))

__device__ __forceinline__ unsigned short f2bf(float f) {
    unsigned int b = __float_as_uint(f);
    unsigned int r = (b + 0x7FFFu + ((b >> 16) & 1u)) >> 16;   // RNE
    return (unsigned short)r;
}
__device__ __forceinline__ float bf2f(unsigned short u) {
    return __uint_as_float((unsigned int)u << 16);
}
__device__ __forceinline__ float4 bfu4(ushort4 u) {
    float4 v;
    v.x = bf2f(u.x); v.y = bf2f(u.y); v.z = bf2f(u.z); v.w = bf2f(u.w);
    return v;
}
// lrelu(e)*a folded: lrelu(e) = 0.6e + 0.4|e| (slope 0.2); abs is a free VOP3 mod
__device__ __forceinline__ float edge_logit(float4 v, float4 fd4, float4 a06, float4 a04) {
    float e0 = v.x + fd4.x, e1 = v.y + fd4.y, e2 = v.z + fd4.z, e3 = v.w + fd4.w;
    return e0 * a06.x + fabsf(e0) * a04.x + e1 * a06.y + fabsf(e1) * a04.y
         + e2 * a06.z + fabsf(e2) * a04.z + e3 * a06.w + fabsf(e3) * a04.w;
}

// ---------------- pass 1: block-local full-range LDS histogram (r5-proven) ----------------
__global__ __launch_bounds__(256) void hist_kernel(const int* __restrict__ dst,
                                                   unsigned* __restrict__ cntmat,
                                                   int* __restrict__ rank, int E) {
    __shared__ unsigned pc[NPAIR];
    int b = blockIdx.x, tid = threadIdx.x;
    for (int k = tid; k < NPAIR; k += 256) pc[k] = 0;
    __syncthreads();
    int beg = b << CSH;
    int end = beg + CHUNK; if (end > E) end = E;
    for (int i = beg + tid; i < end; i += 256) {
        int d = dst[i];
        unsigned sh = (unsigned)(d & 1) << 4;
        unsigned old = atomicAdd(&pc[d >> 1], 1u << sh);
        rank[i] = (int)((old >> sh) & 0xffffu);
    }
    __syncthreads();
    unsigned* o = cntmat + (size_t)b * NPAIR;
    for (int k = tid; k < NPAIR; k += 256) o[k] = pc[k];
}

// ---------------- pass 2 fused: block-prefix + alloc | WtL convert | in_proj ----------------
__global__ __launch_bounds__(256, 4) void prep2_kernel(
        unsigned* __restrict__ cntmat, int HB,
        int* __restrict__ counts, int* __restrict__ row_beg, int* total,
        const float* __restrict__ Ws, const float* __restrict__ Wd,
        unsigned short* __restrict__ WtL,
        const float* __restrict__ x, const float* __restrict__ Win,
        const float* __restrict__ bin, unsigned short* __restrict__ hB) {
    const int PB = (NPAIR + 255) / 256;   // 98
    int blk = blockIdx.x, tid = threadIdx.x;
    if (blk < PB) {
        int p = blk * 256 + tid;
        unsigned run = 0;
        if (p < NPAIR) {
            size_t idx = p;
            #pragma unroll 4
            for (int b = 0; b < HB; ++b, idx += NPAIR) {
                unsigned c = cntmat[idx];
                cntmat[idx] = run;          // exclusive prefix for (block b, pair p)
                run += c;
            }
        }
        int c0 = (int)(run & 0xffffu), c1 = (int)(run >> 16);
        int lane = tid & 63;
        int len = (p < NPAIR) ? (c0 + c1 + 2) : 0;   // both nodes + 2 self loops
        int pscan = len;
        #pragma unroll
        for (int off = 1; off < 64; off <<= 1) {
            int t = __shfl_up(pscan, off);
            if (lane >= off) pscan += t;
        }
        int tot = __shfl(pscan, 63);
        int base = 0;
        if (lane == 63) base = atomicAdd(total, tot);
        base = __shfl(base, 63);
        if (p < NPAIR) {
            int rb = base + pscan - len;
            counts[2 * p] = c0;
            counts[2 * p + 1] = c1;
            row_beg[2 * p] = rb;
            row_beg[2 * p + 1] = rb + c0 + 1;
        }
        return;
    }
    int w = tid >> 6, l = tid & 63;
    int m = l & 15, q = l >> 4;
    if (blk < PB + 384) {
        // --- WtL bf16 transpose-convert (3 layers x [256 cols][128 k]) ---
        int e = (blk - PB) * 256 + tid;  // 0..98303
        int ll = e >> 15;
        int r = e & 32767;
        int colc = r >> 7;
        int k = r & 127;
        float v = (colc < 128) ? Ws[ll * 16384 + k * 128 + colc]
                               : Wd[ll * 16384 + k * 128 + (colc - 128)];
        WtL[ll * 32768 + colc * 128 + k] = f2bf(v);
        return;
    }
    // --- in_proj MFMA: x[N,64] @ W_in[64,128] + b -> hB bf16 (W_in converted inline) ---
    int blk0 = blk - PB - 384;           // 0..511
    short8 B[2][2];
    #pragma unroll
    for (int ct = 0; ct < 2; ++ct) {
        int colw = w * 32 + ct * 16 + m;
        #pragma unroll
        for (int kt = 0; kt < 2; ++kt) {
            short8 a;
            #pragma unroll
            for (int jj = 0; jj < 8; ++jj)
                a[jj] = (short)f2bf(Win[(kt * 32 + q * 8 + jj) * 128 + colw]);
            B[ct][kt] = a;
        }
    }
    float bias[2];
    #pragma unroll
    for (int ct = 0; ct < 2; ++ct) bias[ct] = bin[w * 32 + ct * 16 + m];
    for (int rg = blk0; rg < NN / 16; rg += 512) {
        int row0 = rg * 16;
        const float* ap = x + (size_t)(row0 + m) * 64 + q * 8;
        short8 A[2];
        #pragma unroll
        for (int kt = 0; kt < 2; ++kt) {
            float4 f0 = *(const float4*)(ap + kt * 32);
            float4 f1 = *(const float4*)(ap + kt * 32 + 4);
            short8 a;
            a[0] = (short)f2bf(f0.x); a[1] = (short)f2bf(f0.y);
            a[2] = (short)f2bf(f0.z); a[3] = (short)f2bf(f0.w);
            a[4] = (short)f2bf(f1.x); a[5] = (short)f2bf(f1.y);
            a[6] = (short)f2bf(f1.z); a[7] = (short)f2bf(f1.w);
            A[kt] = a;
        }
        f32x4 acc[2];
        #pragma unroll
        for (int ct = 0; ct < 2; ++ct) acc[ct] = (f32x4){0.f, 0.f, 0.f, 0.f};
        #pragma unroll
        for (int kt = 0; kt < 2; ++kt)
            #pragma unroll
            for (int ct = 0; ct < 2; ++ct)
                acc[ct] = __builtin_amdgcn_mfma_f32_16x16x32_bf16(A[kt], B[ct][kt], acc[ct], 0, 0, 0);
        #pragma unroll
        for (int ct = 0; ct < 2; ++ct) {
            int colw = w * 32 + ct * 16 + m;
            #pragma unroll
            for (int i = 0; i < 4; ++i) {
                int row = row0 + q * 4 + i;
                hB[(size_t)row * 128 + colw] = f2bf(acc[ct][i] + bias[ct]);
            }
        }
    }
}

// ---------------- dual GEMM body (used by scatter_dual + standalone) ----------------
__device__ __forceinline__ void dual_body(const unsigned short* __restrict__ hB,
                                          const unsigned short* __restrict__ Wt,
                                          const float* __restrict__ bs,
                                          const float* __restrict__ bd,
                                          unsigned short* __restrict__ fsB,
                                          unsigned short* __restrict__ fdB,
                                          unsigned short* Atile, int t0, int tstride) {
    int tid = threadIdx.x;
    int w = tid >> 6, l = tid & 63;
    int m = l & 15, q = l >> 4;
    short8 B[4][4];
    #pragma unroll
    for (int ct = 0; ct < 4; ++ct) {
        int colw = w * 64 + ct * 16 + m;
        const unsigned short* wp = Wt + colw * 128 + q * 8;
        #pragma unroll
        for (int kt = 0; kt < 4; ++kt) B[ct][kt] = *(const short8*)(wp + kt * 32);
    }
    const float* bptr = (w < 2) ? bs : bd;
    unsigned short* OUT = (w < 2) ? fsB : fdB;
    int ocb = (w * 64) & 127;
    float bias[4];
    #pragma unroll
    for (int ct = 0; ct < 4; ++ct) bias[ct] = bptr[ocb + ct * 16 + m];

    const int NT = (NN + 63) / 64;   // 782 tiles
    for (int t = t0; t < NT; t += tstride) {
        int row0 = t * 64;
        const char* gsrc = (const char*)(hB + (size_t)row0 * 128);
        #pragma unroll
        for (int c = 0; c < 4; ++c) {
            int off = c * 4096 + tid * 16;
            __builtin_amdgcn_global_load_lds((const GLOBAL_AS void*)(gsrc + off),
                                             (LDS_AS void*)((char*)Atile + off), 16, 0, 0);
        }
        __syncthreads();
        #pragma unroll
        for (int rg = 0; rg < 4; ++rg) {
            const unsigned short* ap = Atile + (rg * 16 + m) * 128 + q * 8;
            short8 A[4];
            #pragma unroll
            for (int kt = 0; kt < 4; ++kt) A[kt] = *(const short8*)(ap + kt * 32);
            f32x4 acc[4];
            #pragma unroll
            for (int ct = 0; ct < 4; ++ct) acc[ct] = (f32x4){0.f, 0.f, 0.f, 0.f};
            #pragma unroll
            for (int kt = 0; kt < 4; ++kt)
                #pragma unroll
                for (int ct = 0; ct < 4; ++ct)
                    acc[ct] = __builtin_amdgcn_mfma_f32_16x16x32_bf16(A[kt], B[ct][kt], acc[ct], 0, 0, 0);
            #pragma unroll
            for (int ct = 0; ct < 4; ++ct) {
                int colw = ocb + ct * 16 + m;
                #pragma unroll
                for (int i = 0; i < 4; ++i) {
                    int row = row0 + rg * 16 + q * 4 + i;
                    if (row < NN) OUT[(size_t)row * 128 + colw] = f2bf(acc[ct][i] + bias[ct]);
                }
            }
        }
        __syncthreads();
    }
}

// fused: CSR scatter (atomic-free) | layer-0 dual GEMM — independent, overlap them.
__global__ __launch_bounds__(256, 4) void scatter_dual_kernel(
        const int* __restrict__ src, const int* __restrict__ dst,
        const int* __restrict__ rank, const int* __restrict__ row_beg,
        const int* __restrict__ counts, const unsigned* __restrict__ cntmat,
        int* __restrict__ col, int E, int n,
        const unsigned short* __restrict__ hB, const unsigned short* __restrict__ Wt,
        const float* __restrict__ bs, const float* __restrict__ bd,
        unsigned short* __restrict__ fsB, unsigned short* __restrict__ fdB) {
    __shared__ unsigned short Atile[64 * 128];   // 16 KB (dual branch only)
    int SB = (E + n + 255) >> 8;
    if ((int)blockIdx.x < SB) {
        int i = blockIdx.x * 256 + threadIdx.x;
        if (i >= E + n) return;
        if (i < E) {
            int d = dst[i];
            int b = i >> CSH;
            unsigned pk = cntmat[(size_t)b * NPAIR + (d >> 1)];
            int off = (int)((pk >> ((unsigned)(d & 1) << 4)) & 0xffffu);
            col[row_beg[d] + off + rank[i]] = src[i];
        } else {
            int v = i - E;
            col[row_beg[v] + counts[v]] = v;
        }
        return;
    }
    dual_body(hB, Wt, bs, bd, fsB, fdB, Atile, blockIdx.x - SB, gridDim.x - SB);
}

// standalone dual (layers 1,2)
__global__ __launch_bounds__(256, 4) void dual_gemm_mfma(const unsigned short* __restrict__ hB,
                                                         const unsigned short* __restrict__ Wt,
                                                         const float* __restrict__ bs,
                                                         const float* __restrict__ bd,
                                                         unsigned short* __restrict__ fsB,
                                                         unsigned short* __restrict__ fdB) {
    __shared__ unsigned short Atile[64 * 128];
    dual_body(hB, Wt, bs, bd, fsB, fdB, Atile, blockIdx.x, gridDim.x);
}

// ---------------- fused gather attention + residual + LN + relu ----------------
// 2 dst nodes/wave, 4 feats/lane, ONE node-pair per wave then exit (r1/r6 lessons:
// persistent loops and block-wide barriers around the gather loop both kill the
// wave-churn MLP). r7: x8 edge ILP main loop (8 gathers in flight halves the
// dependent col->gather rounds); for the LAST layer the graph-mean partial is
// fused: cross-half shfl + tiny LDS stage AFTER the loop (waves at end-of-life,
// max-of-8 coupling only over a ~100cy epilogue, unlike r6's compute-phase barrier).
__global__ __launch_bounds__(256) void agg_ln_kernel(const unsigned short* __restrict__ h_in,
                                                     const unsigned short* __restrict__ fsB,
                                                     const unsigned short* __restrict__ fdB,
                                                     const int* __restrict__ row_beg,
                                                     const int* __restrict__ counts,
                                                     const int* __restrict__ col,
                                                     const float* __restrict__ attn,
                                                     const float* __restrict__ ln_g,
                                                     const float* __restrict__ ln_b,
                                                     unsigned short* __restrict__ hb_out,
                                                     float* __restrict__ hf_out,
                                                     float* __restrict__ partials, int n) {
    __shared__ float part[4][128];   // 2 KB, used only on the hf_out (last) layer
    int gwave = (blockIdx.x * blockDim.x + threadIdx.x) >> 6;
    int wid = threadIdx.x >> 6;
    int lane = threadIdx.x & 63;
    int half = lane >> 5;
    int sub = lane & 31;
    int node = gwave * 2 + half;
    if (node >= n) return;           // never taken at N=50000 (grid exact)
    int f0 = 4 * sub;
    unsigned foff = (unsigned)(f0 * 2);          // byte offset within a 256B bf16 row
    const char* fsp = (const char*)fsB;
    float4 fd4 = bfu4(*(const ushort4*)((const char*)fdB + (((unsigned)node << 8) | foff)));
    float4 h4 = bfu4(*(const ushort4*)((const char*)h_in + (((unsigned)node << 8) | foff)));
    const float4 a4 = *(const float4*)(attn + f0);
    float4 a06, a04;
    a06.x = 0.6f * a4.x; a06.y = 0.6f * a4.y; a06.z = 0.6f * a4.z; a06.w = 0.6f * a4.w;
    a04.x = 0.4f * a4.x; a04.y = 0.4f * a4.y; a04.z = 0.4f * a4.z; a04.w = 0.4f * a4.w;
    int beg = row_beg[node], end = beg + counts[node] + 1;

    float z[4];
    float4 acc[4];
    #pragma unroll
    for (int k = 0; k < 4; ++k) {
        z[k] = 0.f;
        acc[k].x = 0.f; acc[k].y = 0.f; acc[k].z = 0.f; acc[k].w = 0.f;
    }

    int j = beg;
    for (; j + 7 < end; j += 8) {
        int s0 = col[j], s1 = col[j + 1], s2 = col[j + 2], s3 = col[j + 3];
        int s4 = col[j + 4], s5 = col[j + 5], s6 = col[j + 6], s7 = col[j + 7];
        ushort4 u0 = *(const ushort4*)(fsp + (((unsigned)s0 << 8) | foff));
        ushort4 u1 = *(const ushort4*)(fsp + (((unsigned)s1 << 8) | foff));
        ushort4 u2 = *(const ushort4*)(fsp + (((unsigned)s2 << 8) | foff));
        ushort4 u3 = *(const ushort4*)(fsp + (((unsigned)s3 << 8) | foff));
        ushort4 u4 = *(const ushort4*)(fsp + (((unsigned)s4 << 8) | foff));
        ushort4 u5 = *(const ushort4*)(fsp + (((unsigned)s5 << 8) | foff));
        ushort4 u6 = *(const ushort4*)(fsp + (((unsigned)s6 << 8) | foff));
        ushort4 u7 = *(const ushort4*)(fsp + (((unsigned)s7 << 8) | foff));
        float4 v0 = bfu4(u0), v1 = bfu4(u1), v2 = bfu4(u2), v3 = bfu4(u3);
        float4 v4 = bfu4(u4), v5 = bfu4(u5), v6 = bfu4(u6), v7 = bfu4(u7);
        float p0 = edge_logit(v0, fd4, a06, a04);
        float p1 = edge_logit(v1, fd4, a06, a04);
        float p2 = edge_logit(v2, fd4, a06, a04);
        float p3 = edge_logit(v3, fd4, a06, a04);
        float p4 = edge_logit(v4, fd4, a06, a04);
        float p5 = edge_logit(v5, fd4, a06, a04);
        float p6 = edge_logit(v6, fd4, a06, a04);
        float p7 = edge_logit(v7, fd4, a06, a04);
        #pragma unroll
        for (int off = 1; off <= 4; off <<= 1) {
            p0 += __shfl_xor(p0, off); p1 += __shfl_xor(p1, off);
            p2 += __shfl_xor(p2, off); p3 += __shfl_xor(p3, off);
            p4 += __shfl_xor(p4, off); p5 += __shfl_xor(p5, off);
            p6 += __shfl_xor(p6, off); p7 += __shfl_xor(p7, off);
        }
        float w0 = __expf(p0), w1 = __expf(p1), w2 = __expf(p2), w3 = __expf(p3);
        float w4 = __expf(p4), w5 = __expf(p5), w6 = __expf(p6), w7 = __expf(p7);
        z[0] += w0; z[1] += w1; z[2] += w2; z[3] += w3;
        z[0] += w4; z[1] += w5; z[2] += w6; z[3] += w7;
        acc[0].x += w0 * v0.x; acc[0].y += w0 * v0.y; acc[0].z += w0 * v0.z; acc[0].w += w0 * v0.w;
        acc[1].x += w1 * v1.x; acc[1].y += w1 * v1.y; acc[1].z += w1 * v1.z; acc[1].w += w1 * v1.w;
        acc[2].x += w2 * v2.x; acc[2].y += w2 * v2.y; acc[2].z += w2 * v2.z; acc[2].w += w2 * v2.w;
        acc[3].x += w3 * v3.x; acc[3].y += w3 * v3.y; acc[3].z += w3 * v3.z; acc[3].w += w3 * v3.w;
        acc[0].x += w4 * v4.x; acc[0].y += w4 * v4.y; acc[0].z += w4 * v4.z; acc[0].w += w4 * v4.w;
        acc[1].x += w5 * v5.x; acc[1].y += w5 * v5.y; acc[1].z += w5 * v5.z; acc[1].w += w5 * v5.w;
        acc[2].x += w6 * v6.x; acc[2].y += w6 * v6.y; acc[2].z += w6 * v6.z; acc[2].w += w6 * v6.w;
        acc[3].x += w7 * v7.x; acc[3].y += w7 * v7.y; acc[3].z += w7 * v7.z; acc[3].w += w7 * v7.w;
    }
    for (; j + 3 < end; j += 4) {
        int s0 = col[j], s1 = col[j + 1], s2 = col[j + 2], s3 = col[j + 3];
        ushort4 u0 = *(const ushort4*)(fsp + (((unsigned)s0 << 8) | foff));
        ushort4 u1 = *(const ushort4*)(fsp + (((unsigned)s1 << 8) | foff));
        ushort4 u2 = *(const ushort4*)(fsp + (((unsigned)s2 << 8) | foff));
        ushort4 u3 = *(const ushort4*)(fsp + (((unsigned)s3 << 8) | foff));
        float4 v0 = bfu4(u0), v1 = bfu4(u1), v2 = bfu4(u2), v3 = bfu4(u3);
        float p0 = edge_logit(v0, fd4, a06, a04);
        float p1 = edge_logit(v1, fd4, a06, a04);
        float p2 = edge_logit(v2, fd4, a06, a04);
        float p3 = edge_logit(v3, fd4, a06, a04);
        #pragma unroll
        for (int off = 1; off <= 4; off <<= 1) {
            p0 += __shfl_xor(p0, off); p1 += __shfl_xor(p1, off);
            p2 += __shfl_xor(p2, off); p3 += __shfl_xor(p3, off);
        }
        float w0 = __expf(p0), w1 = __expf(p1), w2 = __expf(p2), w3 = __expf(p3);
        z[0] += w0; z[1] += w1; z[2] += w2; z[3] += w3;
        acc[0].x += w0 * v0.x; acc[0].y += w0 * v0.y; acc[0].z += w0 * v0.z; acc[0].w += w0 * v0.w;
        acc[1].x += w1 * v1.x; acc[1].y += w1 * v1.y; acc[1].z += w1 * v1.z; acc[1].w += w1 * v1.w;
        acc[2].x += w2 * v2.x; acc[2].y += w2 * v2.y; acc[2].z += w2 * v2.z; acc[2].w += w2 * v2.w;
        acc[3].x += w3 * v3.x; acc[3].y += w3 * v3.y; acc[3].z += w3 * v3.z; acc[3].w += w3 * v3.w;
    }
    for (; j < end; ++j) {
        int s = col[j];
        ushort4 u = *(const ushort4*)(fsp + (((unsigned)s << 8) | foff));
        float4 v = bfu4(u);
        float p = edge_logit(v, fd4, a06, a04);
        p += __shfl_xor(p, 1);
        p += __shfl_xor(p, 2);
        p += __shfl_xor(p, 4);
        float w = __expf(p);
        z[0] += w;
        acc[0].x += w * v.x; acc[0].y += w * v.y; acc[0].z += w * v.z; acc[0].w += w * v.w;
    }
    float zT = (z[0] + z[1]) + (z[2] + z[3]);
    float axT = (acc[0].x + acc[1].x) + (acc[2].x + acc[3].x);
    float ayT = (acc[0].y + acc[1].y) + (acc[2].y + acc[3].y);
    float azT = (acc[0].z + acc[1].z) + (acc[2].z + acc[3].z);
    float awT = (acc[0].w + acc[1].w) + (acc[2].w + acc[3].w);
    float inv = 1.0f / zT;
    float x0 = 2.f * h4.x + axT * inv;  // h + (aggr + h)
    float x1 = 2.f * h4.y + ayT * inv;
    float x2 = 2.f * h4.z + azT * inv;
    float x3 = 2.f * h4.w + awT * inv;
    float s = (x0 + x1) + (x2 + x3);
    #pragma unroll
    for (int off = 1; off <= 16; off <<= 1) s += __shfl_xor(s, off);
    float mean = s * (1.f / 128.f);
    float d0 = x0 - mean, d1 = x1 - mean, d2 = x2 - mean, d3 = x3 - mean;
    float v = (d0 * d0 + d1 * d1) + (d2 * d2 + d3 * d3);
    #pragma unroll
    for (int off = 1; off <= 16; off <<= 1) v += __shfl_xor(v, off);
    float rstd = rsqrtf(v * (1.f / 128.f) + 1e-5f);
    float4 g4 = *(const float4*)(ln_g + f0);
    float4 bb4 = *(const float4*)(ln_b + f0);
    float4 o;
    o.x = fmaxf(d0 * rstd * g4.x + bb4.x, 0.f);
    o.y = fmaxf(d1 * rstd * g4.y + bb4.y, 0.f);
    o.z = fmaxf(d2 * rstd * g4.z + bb4.z, 0.f);
    o.w = fmaxf(d3 * rstd * g4.w + bb4.w, 0.f);
    if (hf_out) {
        *(float4*)((char*)hf_out + (((unsigned)node << 9) | (unsigned)(f0 * 4))) = o;
        // fused graph-mean partial: sum this block's 8 nodes. Cross-half add first
        // (lane^32 pairs the wave's two nodes), then per-wave LDS row, one barrier,
        // 128 threads emit the block partial. No atomics, no in-loop barriers.
        float4 t = o;
        t.x += __shfl_xor(t.x, 32);
        t.y += __shfl_xor(t.y, 32);
        t.z += __shfl_xor(t.z, 32);
        t.w += __shfl_xor(t.w, 32);
        if (half == 0) *(float4*)(&part[wid][f0]) = t;
        __syncthreads();
        int tt = threadIdx.x;
        if (tt < 128) {
            partials[(size_t)blockIdx.x * 128 + tt] =
                (part[0][tt] + part[1][tt]) + (part[2][tt] + part[3][tt]);
        }
    } else {
        ushort4 ob;
        ob.x = f2bf(o.x); ob.y = f2bf(o.y); ob.z = f2bf(o.z); ob.w = f2bf(o.w);
        *(ushort4*)((char*)hb_out + (((unsigned)node << 8) | foff)) = ob;
    }
}

// ---------------- graph mean finish: reduce 6250 block partials ----------------
__global__ __launch_bounds__(1024) void mean2_kernel(const float* __restrict__ partials,
                                                     float* __restrict__ out, int nb, int n) {
    __shared__ float smem[8][128];
    int c = threadIdx.x & 127;
    int g = threadIdx.x >> 7;  // 0..7
    float acc = 0.f;
    for (int r = g; r < nb; r += 8)
        acc += partials[r * 128 + c];
    smem[g][c] = acc;
    __syncthreads();
    if (threadIdx.x < 128) {
        float s = 0.f;
        #pragma unroll
        for (int k = 0; k < 8; ++k) s += smem[k][c];
        out[c] = s * (1.f / n);
    }
}

extern "C" void kernel_launch(void* const* d_in, const int* in_sizes, int n_in,
                              void* d_out, int out_size, void* d_ws, size_t ws_size,
                              hipStream_t stream) {
    const float* node_feats = (const float*)d_in[0];
    const int* src = (const int*)d_in[1];
    const int* dst = (const int*)d_in[2];
    const float* W_in = (const float*)d_in[3];
    const float* b_in = (const float*)d_in[4];
    const float* W_src = (const float*)d_in[5];
    const float* b_src = (const float*)d_in[6];
    const float* W_dst = (const float*)d_in[7];
    const float* b_dst = (const float*)d_in[8];
    const float* attn = (const float*)d_in[9];
    const float* ln_g = (const float*)d_in[10];
    const float* ln_b = (const float*)d_in[11];
    float* out = (float*)d_out;

    const int N = NN;
    const int E = in_sizes[1];
    const int HB = (E + CHUNK - 1) >> CSH;   // 98 hist blocks @ E=800K

    // workspace layout
    unsigned short* fsB = (unsigned short*)d_ws;      // N*128 bf16
    unsigned short* fdB = fsB + (size_t)N * 128;      // N*128 bf16
    unsigned short* hB = fdB + (size_t)N * 128;       // N*128 bf16
    unsigned short* WtL = hB + (size_t)N * 128;       // 3*256*128 bf16
    unsigned short* WtIn = WtL + 3 * 32768;           // 128*64 bf16 (unused, layout kept)
    int* counts = (int*)(WtIn + 8192);                // N
    int* total = counts + N;                          // 1 (memset)
    int* row_beg = total + 1;                         // N
    int* rankb = row_beg + N;                         // E
    int* colb = rankb + E;                            // E+N
    unsigned* cntmat = (unsigned*)(colb + (E + N));   // HB*NPAIR u32 (~9.8MB)
    float* partials = (float*)(cntmat + (size_t)HB * NPAIR);  // 6250*128 f32 (3.2MB)

    const int NT = (N + 63) / 64;   // 782 dual tiles
    const int AB = (N + 7) / 8;     // 6250 agg blocks (N % 8 == 0: every wave full)

    hipMemsetAsync(total, 0, sizeof(int), stream);

    // --- pass 1: block-local LDS hist (no device atomics) ---
    hist_kernel<<<HB, 256, 0, stream>>>(dst, cntmat, rankb, E);

    // --- pass 2: block-prefix + alloc | WtL convert | in_proj ---
    const int PB = (NPAIR + 255) / 256;   // 98
    prep2_kernel<<<PB + 384 + 512, 256, 0, stream>>>(cntmat, HB, counts, row_beg, total,
                                                     W_src, W_dst, WtL,
                                                     node_feats, W_in, b_in, hB);

    // --- pass 3: scatter | layer-0 dual GEMM ---
    int SB = (E + N + 255) / 256;
    scatter_dual_kernel<<<SB + NT, 256, 0, stream>>>(src, dst, rankb, row_beg,
                                                     counts, cntmat, colb, E, N,
                                                     hB, WtL, b_src, b_dst, fsB, fdB);

    // --- 3 GATv2 layers ---
    for (int l = 0; l < 3; ++l) {
        int last = (l == 2);
        if (l > 0)
            dual_gemm_mfma<<<NT, 256, 0, stream>>>(hB, WtL + (size_t)l * 32768,
                                                   b_src + l * 128, b_dst + l * 128,
                                                   fsB, fdB);
        agg_ln_kernel<<<AB, 256, 0, stream>>>(hB, fsB, fdB, row_beg, counts, colb,
                                              attn + l * 128, ln_g + l * 128,
                                              ln_b + l * 128,
                                              last ? nullptr : hB,
                                              last ? (out + 128) : nullptr,
                                              partials, N);
    }

    // --- graph mean finish into out[0:128] ---
    mean2_kernel<<<1, 1024, 0, stream>>>(partials, out, AB, N);
}

// Round 8
// 366.975 us; speedup vs baseline: 1.5534x; 1.5534x over previous
//
#include <hip/hip_runtime.h>
#include <hip/hip_bf16.h>

#define NN 50000
#define NPAIR 25000     // packed 2x16-bit LDS counters: 25000 u32 = 100KB (<160KB)
#define CSH 13          // hist chunk = 8192 edges/block
#define CHUNK (1 << CSH)

typedef short short8 __attribute__((ext_vector_type(8)));
typedef float f32x4 __attribute__((ext_vector_type(4)));

#define GLOBAL_AS __attribute__((address_space(1)))
#define LDS_AS __attribute__((address_space(3)))

__device__ __forceinline__ unsigned short f2bf(float f) {
    unsigned int b = __float_as_uint(f);
    unsigned int r = (b + 0x7FFFu + ((b >> 16) & 1u)) >> 16;   // RNE
    return (unsigned short)r;
}
__device__ __forceinline__ float bf2f(unsigned short u) {
    return __uint_as_float((unsigned int)u << 16);
}
__device__ __forceinline__ float4 bfu4(ushort4 u) {
    float4 v;
    v.x = bf2f(u.x); v.y = bf2f(u.y); v.z = bf2f(u.z); v.w = bf2f(u.w);
    return v;
}
// lrelu(e)*a folded: lrelu(e) = 0.6e + 0.4|e| (slope 0.2); abs is a free VOP3 mod
__device__ __forceinline__ float edge_logit(float4 v, float4 fd4, float4 a06, float4 a04) {
    float e0 = v.x + fd4.x, e1 = v.y + fd4.y, e2 = v.z + fd4.z, e3 = v.w + fd4.w;
    return e0 * a06.x + fabsf(e0) * a04.x + e1 * a06.y + fabsf(e1) * a04.y
         + e2 * a06.z + fabsf(e2) * a04.z + e3 * a06.w + fabsf(e3) * a04.w;
}

// ---------------- pass 1: block-local full-range LDS histogram (r5-proven) ----------------
__global__ __launch_bounds__(256) void hist_kernel(const int* __restrict__ dst,
                                                   unsigned* __restrict__ cntmat,
                                                   int* __restrict__ rank, int E) {
    __shared__ unsigned pc[NPAIR];
    int b = blockIdx.x, tid = threadIdx.x;
    for (int k = tid; k < NPAIR; k += 256) pc[k] = 0;
    __syncthreads();
    int beg = b << CSH;
    int end = beg + CHUNK; if (end > E) end = E;
    for (int i = beg + tid; i < end; i += 256) {
        int d = dst[i];
        unsigned sh = (unsigned)(d & 1) << 4;
        unsigned old = atomicAdd(&pc[d >> 1], 1u << sh);
        rank[i] = (int)((old >> sh) & 0xffffu);
    }
    __syncthreads();
    unsigned* o = cntmat + (size_t)b * NPAIR;
    for (int k = tid; k < NPAIR; k += 256) o[k] = pc[k];
}

// ---------------- pass 2 fused: block-prefix + alloc | WtL convert | in_proj ----------------
__global__ __launch_bounds__(256, 4) void prep2_kernel(
        unsigned* __restrict__ cntmat, int HB,
        int* __restrict__ counts, int* __restrict__ row_beg, int* total,
        const float* __restrict__ Ws, const float* __restrict__ Wd,
        unsigned short* __restrict__ WtL,
        const float* __restrict__ x, const float* __restrict__ Win,
        const float* __restrict__ bin, unsigned short* __restrict__ hB) {
    const int PB = (NPAIR + 255) / 256;   // 98
    int blk = blockIdx.x, tid = threadIdx.x;
    if (blk < PB) {
        int p = blk * 256 + tid;
        unsigned run = 0;
        if (p < NPAIR) {
            size_t idx = p;
            #pragma unroll 4
            for (int b = 0; b < HB; ++b, idx += NPAIR) {
                unsigned c = cntmat[idx];
                cntmat[idx] = run;          // exclusive prefix for (block b, pair p)
                run += c;
            }
        }
        int c0 = (int)(run & 0xffffu), c1 = (int)(run >> 16);
        int lane = tid & 63;
        int len = (p < NPAIR) ? (c0 + c1 + 2) : 0;   // both nodes + 2 self loops
        int pscan = len;
        #pragma unroll
        for (int off = 1; off < 64; off <<= 1) {
            int t = __shfl_up(pscan, off);
            if (lane >= off) pscan += t;
        }
        int tot = __shfl(pscan, 63);
        int base = 0;
        if (lane == 63) base = atomicAdd(total, tot);
        base = __shfl(base, 63);
        if (p < NPAIR) {
            int rb = base + pscan - len;
            counts[2 * p] = c0;
            counts[2 * p + 1] = c1;
            row_beg[2 * p] = rb;
            row_beg[2 * p + 1] = rb + c0 + 1;
        }
        return;
    }
    int w = tid >> 6, l = tid & 63;
    int m = l & 15, q = l >> 4;
    if (blk < PB + 384) {
        // --- WtL bf16 transpose-convert (3 layers x [256 cols][128 k]) ---
        int e = (blk - PB) * 256 + tid;  // 0..98303
        int ll = e >> 15;
        int r = e & 32767;
        int colc = r >> 7;
        int k = r & 127;
        float v = (colc < 128) ? Ws[ll * 16384 + k * 128 + colc]
                               : Wd[ll * 16384 + k * 128 + (colc - 128)];
        WtL[ll * 32768 + colc * 128 + k] = f2bf(v);
        return;
    }
    // --- in_proj MFMA: x[N,64] @ W_in[64,128] + b -> hB bf16 (W_in converted inline) ---
    int blk0 = blk - PB - 384;           // 0..511
    short8 B[2][2];
    #pragma unroll
    for (int ct = 0; ct < 2; ++ct) {
        int colw = w * 32 + ct * 16 + m;
        #pragma unroll
        for (int kt = 0; kt < 2; ++kt) {
            short8 a;
            #pragma unroll
            for (int jj = 0; jj < 8; ++jj)
                a[jj] = (short)f2bf(Win[(kt * 32 + q * 8 + jj) * 128 + colw]);
            B[ct][kt] = a;
        }
    }
    float bias[2];
    #pragma unroll
    for (int ct = 0; ct < 2; ++ct) bias[ct] = bin[w * 32 + ct * 16 + m];
    for (int rg = blk0; rg < NN / 16; rg += 512) {
        int row0 = rg * 16;
        const float* ap = x + (size_t)(row0 + m) * 64 + q * 8;
        short8 A[2];
        #pragma unroll
        for (int kt = 0; kt < 2; ++kt) {
            float4 f0 = *(const float4*)(ap + kt * 32);
            float4 f1 = *(const float4*)(ap + kt * 32 + 4);
            short8 a;
            a[0] = (short)f2bf(f0.x); a[1] = (short)f2bf(f0.y);
            a[2] = (short)f2bf(f0.z); a[3] = (short)f2bf(f0.w);
            a[4] = (short)f2bf(f1.x); a[5] = (short)f2bf(f1.y);
            a[6] = (short)f2bf(f1.z); a[7] = (short)f2bf(f1.w);
            A[kt] = a;
        }
        f32x4 acc[2];
        #pragma unroll
        for (int ct = 0; ct < 2; ++ct) acc[ct] = (f32x4){0.f, 0.f, 0.f, 0.f};
        #pragma unroll
        for (int kt = 0; kt < 2; ++kt)
            #pragma unroll
            for (int ct = 0; ct < 2; ++ct)
                acc[ct] = __builtin_amdgcn_mfma_f32_16x16x32_bf16(A[kt], B[ct][kt], acc[ct], 0, 0, 0);
        #pragma unroll
        for (int ct = 0; ct < 2; ++ct) {
            int colw = w * 32 + ct * 16 + m;
            #pragma unroll
            for (int i = 0; i < 4; ++i) {
                int row = row0 + q * 4 + i;
                hB[(size_t)row * 128 + colw] = f2bf(acc[ct][i] + bias[ct]);
            }
        }
    }
}

// ---------------- dual GEMM body (used by scatter_dual + standalone) ----------------
__device__ __forceinline__ void dual_body(const unsigned short* __restrict__ hB,
                                          const unsigned short* __restrict__ Wt,
                                          const float* __restrict__ bs,
                                          const float* __restrict__ bd,
                                          unsigned short* __restrict__ fsB,
                                          unsigned short* __restrict__ fdB,
                                          unsigned short* Atile, int t0, int tstride) {
    int tid = threadIdx.x;
    int w = tid >> 6, l = tid & 63;
    int m = l & 15, q = l >> 4;
    short8 B[4][4];
    #pragma unroll
    for (int ct = 0; ct < 4; ++ct) {
        int colw = w * 64 + ct * 16 + m;
        const unsigned short* wp = Wt + colw * 128 + q * 8;
        #pragma unroll
        for (int kt = 0; kt < 4; ++kt) B[ct][kt] = *(const short8*)(wp + kt * 32);
    }
    const float* bptr = (w < 2) ? bs : bd;
    unsigned short* OUT = (w < 2) ? fsB : fdB;
    int ocb = (w * 64) & 127;
    float bias[4];
    #pragma unroll
    for (int ct = 0; ct < 4; ++ct) bias[ct] = bptr[ocb + ct * 16 + m];

    const int NT = (NN + 63) / 64;   // 782 tiles
    for (int t = t0; t < NT; t += tstride) {
        int row0 = t * 64;
        const char* gsrc = (const char*)(hB + (size_t)row0 * 128);
        #pragma unroll
        for (int c = 0; c < 4; ++c) {
            int off = c * 4096 + tid * 16;
            __builtin_amdgcn_global_load_lds((const GLOBAL_AS void*)(gsrc + off),
                                             (LDS_AS void*)((char*)Atile + off), 16, 0, 0);
        }
        __syncthreads();
        #pragma unroll
        for (int rg = 0; rg < 4; ++rg) {
            const unsigned short* ap = Atile + (rg * 16 + m) * 128 + q * 8;
            short8 A[4];
            #pragma unroll
            for (int kt = 0; kt < 4; ++kt) A[kt] = *(const short8*)(ap + kt * 32);
            f32x4 acc[4];
            #pragma unroll
            for (int ct = 0; ct < 4; ++ct) acc[ct] = (f32x4){0.f, 0.f, 0.f, 0.f};
            #pragma unroll
            for (int kt = 0; kt < 4; ++kt)
                #pragma unroll
                for (int ct = 0; ct < 4; ++ct)
                    acc[ct] = __builtin_amdgcn_mfma_f32_16x16x32_bf16(A[kt], B[ct][kt], acc[ct], 0, 0, 0);
            #pragma unroll
            for (int ct = 0; ct < 4; ++ct) {
                int colw = ocb + ct * 16 + m;
                #pragma unroll
                for (int i = 0; i < 4; ++i) {
                    int row = row0 + rg * 16 + q * 4 + i;
                    if (row < NN) OUT[(size_t)row * 128 + colw] = f2bf(acc[ct][i] + bias[ct]);
                }
            }
        }
        __syncthreads();
    }
}

// fused: CSR scatter (atomic-free) | layer-0 dual GEMM — independent, overlap them.
__global__ __launch_bounds__(256, 4) void scatter_dual_kernel(
        const int* __restrict__ src, const int* __restrict__ dst,
        const int* __restrict__ rank, const int* __restrict__ row_beg,
        const int* __restrict__ counts, const unsigned* __restrict__ cntmat,
        int* __restrict__ col, int E, int n,
        const unsigned short* __restrict__ hB, const unsigned short* __restrict__ Wt,
        const float* __restrict__ bs, const float* __restrict__ bd,
        unsigned short* __restrict__ fsB, unsigned short* __restrict__ fdB) {
    __shared__ unsigned short Atile[64 * 128];   // 16 KB (dual branch only)
    int SB = (E + n + 255) >> 8;
    if ((int)blockIdx.x < SB) {
        int i = blockIdx.x * 256 + threadIdx.x;
        if (i >= E + n) return;
        if (i < E) {
            int d = dst[i];
            int b = i >> CSH;
            unsigned pk = cntmat[(size_t)b * NPAIR + (d >> 1)];
            int off = (int)((pk >> ((unsigned)(d & 1) << 4)) & 0xffffu);
            col[row_beg[d] + off + rank[i]] = src[i];
        } else {
            int v = i - E;
            col[row_beg[v] + counts[v]] = v;
        }
        return;
    }
    dual_body(hB, Wt, bs, bd, fsB, fdB, Atile, blockIdx.x - SB, gridDim.x - SB);
}

// standalone dual (layers 1,2)
__global__ __launch_bounds__(256, 4) void dual_gemm_mfma(const unsigned short* __restrict__ hB,
                                                         const unsigned short* __restrict__ Wt,
                                                         const float* __restrict__ bs,
                                                         const float* __restrict__ bd,
                                                         unsigned short* __restrict__ fsB,
                                                         unsigned short* __restrict__ fdB) {
    __shared__ unsigned short Atile[64 * 128];
    dual_body(hB, Wt, bs, bd, fsB, fdB, Atile, blockIdx.x, gridDim.x);
}

// ---------------- fused gather attention + residual + LN + relu ----------------
// 2 dst nodes/wave, 4 feats/lane, ONE node-pair per wave then exit (r1/r6 lessons:
// persistent loops and block-wide barriers around the gather loop both kill the
// wave-churn MLP). r7-proven: x8 edge ILP main loop (+~35us over x4 across the 3
// layers); last layer fuses graph-mean block partials (cross-half shfl + 2KB LDS
// stage AFTER the loop -- end-of-life coupling only).
__global__ __launch_bounds__(256) void agg_ln_kernel(const unsigned short* __restrict__ h_in,
                                                     const unsigned short* __restrict__ fsB,
                                                     const unsigned short* __restrict__ fdB,
                                                     const int* __restrict__ row_beg,
                                                     const int* __restrict__ counts,
                                                     const int* __restrict__ col,
                                                     const float* __restrict__ attn,
                                                     const float* __restrict__ ln_g,
                                                     const float* __restrict__ ln_b,
                                                     unsigned short* __restrict__ hb_out,
                                                     float* __restrict__ hf_out,
                                                     float* __restrict__ partials, int n) {
    __shared__ float part[4][128];   // 2 KB, used only on the hf_out (last) layer
    int gwave = (blockIdx.x * blockDim.x + threadIdx.x) >> 6;
    int wid = threadIdx.x >> 6;
    int lane = threadIdx.x & 63;
    int half = lane >> 5;
    int sub = lane & 31;
    int node = gwave * 2 + half;
    if (node >= n) return;           // never taken at N=50000 (grid exact)
    int f0 = 4 * sub;
    unsigned foff = (unsigned)(f0 * 2);          // byte offset within a 256B bf16 row
    const char* fsp = (const char*)fsB;
    float4 fd4 = bfu4(*(const ushort4*)((const char*)fdB + (((unsigned)node << 8) | foff)));
    float4 h4 = bfu4(*(const ushort4*)((const char*)h_in + (((unsigned)node << 8) | foff)));
    const float4 a4 = *(const float4*)(attn + f0);
    float4 a06, a04;
    a06.x = 0.6f * a4.x; a06.y = 0.6f * a4.y; a06.z = 0.6f * a4.z; a06.w = 0.6f * a4.w;
    a04.x = 0.4f * a4.x; a04.y = 0.4f * a4.y; a04.z = 0.4f * a4.z; a04.w = 0.4f * a4.w;
    int beg = row_beg[node], end = beg + counts[node] + 1;

    float z[4];
    float4 acc[4];
    #pragma unroll
    for (int k = 0; k < 4; ++k) {
        z[k] = 0.f;
        acc[k].x = 0.f; acc[k].y = 0.f; acc[k].z = 0.f; acc[k].w = 0.f;
    }

    int j = beg;
    for (; j + 7 < end; j += 8) {
        int s0 = col[j], s1 = col[j + 1], s2 = col[j + 2], s3 = col[j + 3];
        int s4 = col[j + 4], s5 = col[j + 5], s6 = col[j + 6], s7 = col[j + 7];
        ushort4 u0 = *(const ushort4*)(fsp + (((unsigned)s0 << 8) | foff));
        ushort4 u1 = *(const ushort4*)(fsp + (((unsigned)s1 << 8) | foff));
        ushort4 u2 = *(const ushort4*)(fsp + (((unsigned)s2 << 8) | foff));
        ushort4 u3 = *(const ushort4*)(fsp + (((unsigned)s3 << 8) | foff));
        ushort4 u4 = *(const ushort4*)(fsp + (((unsigned)s4 << 8) | foff));
        ushort4 u5 = *(const ushort4*)(fsp + (((unsigned)s5 << 8) | foff));
        ushort4 u6 = *(const ushort4*)(fsp + (((unsigned)s6 << 8) | foff));
        ushort4 u7 = *(const ushort4*)(fsp + (((unsigned)s7 << 8) | foff));
        float4 v0 = bfu4(u0), v1 = bfu4(u1), v2 = bfu4(u2), v3 = bfu4(u3);
        float4 v4 = bfu4(u4), v5 = bfu4(u5), v6 = bfu4(u6), v7 = bfu4(u7);
        float p0 = edge_logit(v0, fd4, a06, a04);
        float p1 = edge_logit(v1, fd4, a06, a04);
        float p2 = edge_logit(v2, fd4, a06, a04);
        float p3 = edge_logit(v3, fd4, a06, a04);
        float p4 = edge_logit(v4, fd4, a06, a04);
        float p5 = edge_logit(v5, fd4, a06, a04);
        float p6 = edge_logit(v6, fd4, a06, a04);
        float p7 = edge_logit(v7, fd4, a06, a04);
        #pragma unroll
        for (int off = 1; off <= 4; off <<= 1) {
            p0 += __shfl_xor(p0, off); p1 += __shfl_xor(p1, off);
            p2 += __shfl_xor(p2, off); p3 += __shfl_xor(p3, off);
            p4 += __shfl_xor(p4, off); p5 += __shfl_xor(p5, off);
            p6 += __shfl_xor(p6, off); p7 += __shfl_xor(p7, off);
        }
        float w0 = __expf(p0), w1 = __expf(p1), w2 = __expf(p2), w3 = __expf(p3);
        float w4 = __expf(p4), w5 = __expf(p5), w6 = __expf(p6), w7 = __expf(p7);
        z[0] += w0; z[1] += w1; z[2] += w2; z[3] += w3;
        z[0] += w4; z[1] += w5; z[2] += w6; z[3] += w7;
        acc[0].x += w0 * v0.x; acc[0].y += w0 * v0.y; acc[0].z += w0 * v0.z; acc[0].w += w0 * v0.w;
        acc[1].x += w1 * v1.x; acc[1].y += w1 * v1.y; acc[1].z += w1 * v1.z; acc[1].w += w1 * v1.w;
        acc[2].x += w2 * v2.x; acc[2].y += w2 * v2.y; acc[2].z += w2 * v2.z; acc[2].w += w2 * v2.w;
        acc[3].x += w3 * v3.x; acc[3].y += w3 * v3.y; acc[3].z += w3 * v3.z; acc[3].w += w3 * v3.w;
        acc[0].x += w4 * v4.x; acc[0].y += w4 * v4.y; acc[0].z += w4 * v4.z; acc[0].w += w4 * v4.w;
        acc[1].x += w5 * v5.x; acc[1].y += w5 * v5.y; acc[1].z += w5 * v5.z; acc[1].w += w5 * v5.w;
        acc[2].x += w6 * v6.x; acc[2].y += w6 * v6.y; acc[2].z += w6 * v6.z; acc[2].w += w6 * v6.w;
        acc[3].x += w7 * v7.x; acc[3].y += w7 * v7.y; acc[3].z += w7 * v7.z; acc[3].w += w7 * v7.w;
    }
    for (; j + 3 < end; j += 4) {
        int s0 = col[j], s1 = col[j + 1], s2 = col[j + 2], s3 = col[j + 3];
        ushort4 u0 = *(const ushort4*)(fsp + (((unsigned)s0 << 8) | foff));
        ushort4 u1 = *(const ushort4*)(fsp + (((unsigned)s1 << 8) | foff));
        ushort4 u2 = *(const ushort4*)(fsp + (((unsigned)s2 << 8) | foff));
        ushort4 u3 = *(const ushort4*)(fsp + (((unsigned)s3 << 8) | foff));
        float4 v0 = bfu4(u0), v1 = bfu4(u1), v2 = bfu4(u2), v3 = bfu4(u3);
        float p0 = edge_logit(v0, fd4, a06, a04);
        float p1 = edge_logit(v1, fd4, a06, a04);
        float p2 = edge_logit(v2, fd4, a06, a04);
        float p3 = edge_logit(v3, fd4, a06, a04);
        #pragma unroll
        for (int off = 1; off <= 4; off <<= 1) {
            p0 += __shfl_xor(p0, off); p1 += __shfl_xor(p1, off);
            p2 += __shfl_xor(p2, off); p3 += __shfl_xor(p3, off);
        }
        float w0 = __expf(p0), w1 = __expf(p1), w2 = __expf(p2), w3 = __expf(p3);
        z[0] += w0; z[1] += w1; z[2] += w2; z[3] += w3;
        acc[0].x += w0 * v0.x; acc[0].y += w0 * v0.y; acc[0].z += w0 * v0.z; acc[0].w += w0 * v0.w;
        acc[1].x += w1 * v1.x; acc[1].y += w1 * v1.y; acc[1].z += w1 * v1.z; acc[1].w += w1 * v1.w;
        acc[2].x += w2 * v2.x; acc[2].y += w2 * v2.y; acc[2].z += w2 * v2.z; acc[2].w += w2 * v2.w;
        acc[3].x += w3 * v3.x; acc[3].y += w3 * v3.y; acc[3].z += w3 * v3.z; acc[3].w += w3 * v3.w;
    }
    for (; j < end; ++j) {
        int s = col[j];
        ushort4 u = *(const ushort4*)(fsp + (((unsigned)s << 8) | foff));
        float4 v = bfu4(u);
        float p = edge_logit(v, fd4, a06, a04);
        p += __shfl_xor(p, 1);
        p += __shfl_xor(p, 2);
        p += __shfl_xor(p, 4);
        float w = __expf(p);
        z[0] += w;
        acc[0].x += w * v.x; acc[0].y += w * v.y; acc[0].z += w * v.z; acc[0].w += w * v.w;
    }
    float zT = (z[0] + z[1]) + (z[2] + z[3]);
    float axT = (acc[0].x + acc[1].x) + (acc[2].x + acc[3].x);
    float ayT = (acc[0].y + acc[1].y) + (acc[2].y + acc[3].y);
    float azT = (acc[0].z + acc[1].z) + (acc[2].z + acc[3].z);
    float awT = (acc[0].w + acc[1].w) + (acc[2].w + acc[3].w);
    float inv = 1.0f / zT;
    float x0 = 2.f * h4.x + axT * inv;  // h + (aggr + h)
    float x1 = 2.f * h4.y + ayT * inv;
    float x2 = 2.f * h4.z + azT * inv;
    float x3 = 2.f * h4.w + awT * inv;
    float s = (x0 + x1) + (x2 + x3);
    #pragma unroll
    for (int off = 1; off <= 16; off <<= 1) s += __shfl_xor(s, off);
    float mean = s * (1.f / 128.f);
    float d0 = x0 - mean, d1 = x1 - mean, d2 = x2 - mean, d3 = x3 - mean;
    float v = (d0 * d0 + d1 * d1) + (d2 * d2 + d3 * d3);
    #pragma unroll
    for (int off = 1; off <= 16; off <<= 1) v += __shfl_xor(v, off);
    float rstd = rsqrtf(v * (1.f / 128.f) + 1e-5f);
    float4 g4 = *(const float4*)(ln_g + f0);
    float4 bb4 = *(const float4*)(ln_b + f0);
    float4 o;
    o.x = fmaxf(d0 * rstd * g4.x + bb4.x, 0.f);
    o.y = fmaxf(d1 * rstd * g4.y + bb4.y, 0.f);
    o.z = fmaxf(d2 * rstd * g4.z + bb4.z, 0.f);
    o.w = fmaxf(d3 * rstd * g4.w + bb4.w, 0.f);
    if (hf_out) {
        *(float4*)((char*)hf_out + (((unsigned)node << 9) | (unsigned)(f0 * 4))) = o;
        // fused graph-mean partial: sum this block's 8 nodes. Cross-half add first
        // (lane^32 pairs the wave's two nodes), then per-wave LDS row, one barrier,
        // 128 threads emit the block partial. No atomics, no in-loop barriers.
        float4 t = o;
        t.x += __shfl_xor(t.x, 32);
        t.y += __shfl_xor(t.y, 32);
        t.z += __shfl_xor(t.z, 32);
        t.w += __shfl_xor(t.w, 32);
        if (half == 0) *(float4*)(&part[wid][f0]) = t;
        __syncthreads();
        int tt = threadIdx.x;
        if (tt < 128) {
            partials[(size_t)blockIdx.x * 128 + tt] =
                (part[0][tt] + part[1][tt]) + (part[2][tt] + part[3][tt]);
        }
    } else {
        ushort4 ob;
        ob.x = f2bf(o.x); ob.y = f2bf(o.y); ob.z = f2bf(o.z); ob.w = f2bf(o.w);
        *(ushort4*)((char*)hb_out + (((unsigned)node << 8) | foff)) = ob;
    }
}

// ---------------- graph mean finish: 6250 partials -> 256 -> 1 (r7 bug: the
// single-block mean2 serially read 3.2MB at 1-CU bandwidth = 223us. Two-stage.) ----
__global__ __launch_bounds__(128) void mean_r1_kernel(const float* __restrict__ partials,
                                                      float* __restrict__ partials2, int nb) {
    int c = threadIdx.x;
    float acc = 0.f;
    for (int r = blockIdx.x; r < nb; r += gridDim.x)
        acc += partials[(size_t)r * 128 + c];
    partials2[blockIdx.x * 128 + c] = acc;
}

__global__ __launch_bounds__(1024) void mean2_kernel(const float* __restrict__ partials,
                                                     float* __restrict__ out, int nb, int n) {
    __shared__ float smem[8][128];
    int c = threadIdx.x & 127;
    int g = threadIdx.x >> 7;  // 0..7
    float acc = 0.f;
    for (int r = g; r < nb; r += 8)
        acc += partials[r * 128 + c];
    smem[g][c] = acc;
    __syncthreads();
    if (threadIdx.x < 128) {
        float s = 0.f;
        #pragma unroll
        for (int k = 0; k < 8; ++k) s += smem[k][c];
        out[c] = s * (1.f / n);
    }
}

extern "C" void kernel_launch(void* const* d_in, const int* in_sizes, int n_in,
                              void* d_out, int out_size, void* d_ws, size_t ws_size,
                              hipStream_t stream) {
    const float* node_feats = (const float*)d_in[0];
    const int* src = (const int*)d_in[1];
    const int* dst = (const int*)d_in[2];
    const float* W_in = (const float*)d_in[3];
    const float* b_in = (const float*)d_in[4];
    const float* W_src = (const float*)d_in[5];
    const float* b_src = (const float*)d_in[6];
    const float* W_dst = (const float*)d_in[7];
    const float* b_dst = (const float*)d_in[8];
    const float* attn = (const float*)d_in[9];
    const float* ln_g = (const float*)d_in[10];
    const float* ln_b = (const float*)d_in[11];
    float* out = (float*)d_out;

    const int N = NN;
    const int E = in_sizes[1];
    const int HB = (E + CHUNK - 1) >> CSH;   // 98 hist blocks @ E=800K

    // workspace layout
    unsigned short* fsB = (unsigned short*)d_ws;      // N*128 bf16
    unsigned short* fdB = fsB + (size_t)N * 128;      // N*128 bf16
    unsigned short* hB = fdB + (size_t)N * 128;       // N*128 bf16
    unsigned short* WtL = hB + (size_t)N * 128;       // 3*256*128 bf16
    unsigned short* WtIn = WtL + 3 * 32768;           // 128*64 bf16 (unused, layout kept)
    int* counts = (int*)(WtIn + 8192);                // N
    int* total = counts + N;                          // 1 (memset)
    int* row_beg = total + 1;                         // N
    int* rankb = row_beg + N;                         // E
    int* colb = rankb + E;                            // E+N
    unsigned* cntmat = (unsigned*)(colb + (E + N));   // HB*NPAIR u32 (~9.8MB)
    float* partials = (float*)(cntmat + (size_t)HB * NPAIR);  // 6250*128 f32 (3.2MB)
    float* partials2 = partials + (size_t)6250 * 128;         // 256*128 f32

    const int NT = (N + 63) / 64;   // 782 dual tiles
    const int AB = (N + 7) / 8;     // 6250 agg blocks (N % 8 == 0: every wave full)

    hipMemsetAsync(total, 0, sizeof(int), stream);

    // --- pass 1: block-local LDS hist (no device atomics) ---
    hist_kernel<<<HB, 256, 0, stream>>>(dst, cntmat, rankb, E);

    // --- pass 2: block-prefix + alloc | WtL convert | in_proj ---
    const int PB = (NPAIR + 255) / 256;   // 98
    prep2_kernel<<<PB + 384 + 512, 256, 0, stream>>>(cntmat, HB, counts, row_beg, total,
                                                     W_src, W_dst, WtL,
                                                     node_feats, W_in, b_in, hB);

    // --- pass 3: scatter | layer-0 dual GEMM ---
    int SB = (E + N + 255) / 256;
    scatter_dual_kernel<<<SB + NT, 256, 0, stream>>>(src, dst, rankb, row_beg,
                                                     counts, cntmat, colb, E, N,
                                                     hB, WtL, b_src, b_dst, fsB, fdB);

    // --- 3 GATv2 layers ---
    for (int l = 0; l < 3; ++l) {
        int last = (l == 2);
        if (l > 0)
            dual_gemm_mfma<<<NT, 256, 0, stream>>>(hB, WtL + (size_t)l * 32768,
                                                   b_src + l * 128, b_dst + l * 128,
                                                   fsB, fdB);
        agg_ln_kernel<<<AB, 256, 0, stream>>>(hB, fsB, fdB, row_beg, counts, colb,
                                              attn + l * 128, ln_g + l * 128,
                                              ln_b + l * 128,
                                              last ? nullptr : hB,
                                              last ? (out + 128) : nullptr,
                                              partials, N);
    }

    // --- graph mean finish into out[0:128] (two-stage over block partials) ---
    mean_r1_kernel<<<256, 128, 0, stream>>>(partials, partials2, AB);
    mean2_kernel<<<1, 1024, 0, stream>>>(partials2, out, 256, N);
}

// Round 9
// 362.336 us; speedup vs baseline: 1.5733x; 1.0128x over previous
//
#include <hip/hip_runtime.h>
#include <hip/hip_bf16.h>

#define NN 50000
#define NPAIR 25000     // packed 2x16-bit LDS counters: 25000 u32 = 100KB (<160KB)
#define CSH 13          // hist chunk = 8192 edges/block
#define CHUNK (1 << CSH)

typedef short short8 __attribute__((ext_vector_type(8)));
typedef float f32x4 __attribute__((ext_vector_type(4)));

#define GLOBAL_AS __attribute__((address_space(1)))
#define LDS_AS __attribute__((address_space(3)))

__device__ __forceinline__ unsigned short f2bf(float f) {
    unsigned int b = __float_as_uint(f);
    unsigned int r = (b + 0x7FFFu + ((b >> 16) & 1u)) >> 16;   // RNE
    return (unsigned short)r;
}
__device__ __forceinline__ float bf2f(unsigned short u) {
    return __uint_as_float((unsigned int)u << 16);
}
__device__ __forceinline__ float4 bfu4(ushort4 u) {
    float4 v;
    v.x = bf2f(u.x); v.y = bf2f(u.y); v.z = bf2f(u.z); v.w = bf2f(u.w);
    return v;
}
// lrelu(e)*a folded: lrelu(e) = 0.6e + 0.4|e| (slope 0.2); abs is a free VOP3 mod
__device__ __forceinline__ float edge_logit(float4 v, float4 fd4, float4 a06, float4 a04) {
    float e0 = v.x + fd4.x, e1 = v.y + fd4.y, e2 = v.z + fd4.z, e3 = v.w + fd4.w;
    return e0 * a06.x + fabsf(e0) * a04.x + e1 * a06.y + fabsf(e1) * a04.y
         + e2 * a06.z + fabsf(e2) * a04.z + e3 * a06.w + fabsf(e3) * a04.w;
}

// ---------------- pass 1: block-local full-range LDS histogram (r5-proven) ----------------
__global__ __launch_bounds__(256) void hist_kernel(const int* __restrict__ dst,
                                                   unsigned* __restrict__ cntmat,
                                                   int* __restrict__ rank, int E) {
    __shared__ unsigned pc[NPAIR];
    int b = blockIdx.x, tid = threadIdx.x;
    for (int k = tid; k < NPAIR; k += 256) pc[k] = 0;
    __syncthreads();
    int beg = b << CSH;
    int end = beg + CHUNK; if (end > E) end = E;
    for (int i = beg + tid; i < end; i += 256) {
        int d = dst[i];
        unsigned sh = (unsigned)(d & 1) << 4;
        unsigned old = atomicAdd(&pc[d >> 1], 1u << sh);
        rank[i] = (int)((old >> sh) & 0xffffu);
    }
    __syncthreads();
    unsigned* o = cntmat + (size_t)b * NPAIR;
    for (int k = tid; k < NPAIR; k += 256) o[k] = pc[k];
}

// ---------------- pass 2 fused: block-prefix + alloc | WtL convert | in_proj ----------------
__global__ __launch_bounds__(256, 4) void prep2_kernel(
        unsigned* __restrict__ cntmat, int HB,
        int* __restrict__ counts, int* __restrict__ row_beg, int* total,
        const float* __restrict__ Ws, const float* __restrict__ Wd,
        unsigned short* __restrict__ WtL,
        const float* __restrict__ x, const float* __restrict__ Win,
        const float* __restrict__ bin, unsigned short* __restrict__ hB) {
    const int PB = (NPAIR + 255) / 256;   // 98
    int blk = blockIdx.x, tid = threadIdx.x;
    if (blk < PB) {
        int p = blk * 256 + tid;
        unsigned run = 0;
        if (p < NPAIR) {
            size_t idx = p;
            #pragma unroll 4
            for (int b = 0; b < HB; ++b, idx += NPAIR) {
                unsigned c = cntmat[idx];
                cntmat[idx] = run;          // exclusive prefix for (block b, pair p)
                run += c;
            }
        }
        int c0 = (int)(run & 0xffffu), c1 = (int)(run >> 16);
        int lane = tid & 63;
        int len = (p < NPAIR) ? (c0 + c1 + 2) : 0;   // both nodes + 2 self loops
        int pscan = len;
        #pragma unroll
        for (int off = 1; off < 64; off <<= 1) {
            int t = __shfl_up(pscan, off);
            if (lane >= off) pscan += t;
        }
        int tot = __shfl(pscan, 63);
        int base = 0;
        if (lane == 63) base = atomicAdd(total, tot);
        base = __shfl(base, 63);
        if (p < NPAIR) {
            int rb = base + pscan - len;
            counts[2 * p] = c0;
            counts[2 * p + 1] = c1;
            row_beg[2 * p] = rb;
            row_beg[2 * p + 1] = rb + c0 + 1;
        }
        return;
    }
    int w = tid >> 6, l = tid & 63;
    int m = l & 15, q = l >> 4;
    if (blk < PB + 384) {
        // --- WtL bf16 transpose-convert (3 layers x [256 cols][128 k]) ---
        int e = (blk - PB) * 256 + tid;  // 0..98303
        int ll = e >> 15;
        int r = e & 32767;
        int colc = r >> 7;
        int k = r & 127;
        float v = (colc < 128) ? Ws[ll * 16384 + k * 128 + colc]
                               : Wd[ll * 16384 + k * 128 + (colc - 128)];
        WtL[ll * 32768 + colc * 128 + k] = f2bf(v);
        return;
    }
    // --- in_proj MFMA: x[N,64] @ W_in[64,128] + b -> hB bf16 (W_in converted inline) ---
    int blk0 = blk - PB - 384;           // 0..511
    short8 B[2][2];
    #pragma unroll
    for (int ct = 0; ct < 2; ++ct) {
        int colw = w * 32 + ct * 16 + m;
        #pragma unroll
        for (int kt = 0; kt < 2; ++kt) {
            short8 a;
            #pragma unroll
            for (int jj = 0; jj < 8; ++jj)
                a[jj] = (short)f2bf(Win[(kt * 32 + q * 8 + jj) * 128 + colw]);
            B[ct][kt] = a;
        }
    }
    float bias[2];
    #pragma unroll
    for (int ct = 0; ct < 2; ++ct) bias[ct] = bin[w * 32 + ct * 16 + m];
    for (int rg = blk0; rg < NN / 16; rg += 512) {
        int row0 = rg * 16;
        const float* ap = x + (size_t)(row0 + m) * 64 + q * 8;
        short8 A[2];
        #pragma unroll
        for (int kt = 0; kt < 2; ++kt) {
            float4 f0 = *(const float4*)(ap + kt * 32);
            float4 f1 = *(const float4*)(ap + kt * 32 + 4);
            short8 a;
            a[0] = (short)f2bf(f0.x); a[1] = (short)f2bf(f0.y);
            a[2] = (short)f2bf(f0.z); a[3] = (short)f2bf(f0.w);
            a[4] = (short)f2bf(f1.x); a[5] = (short)f2bf(f1.y);
            a[6] = (short)f2bf(f1.z); a[7] = (short)f2bf(f1.w);
            A[kt] = a;
        }
        f32x4 acc[2];
        #pragma unroll
        for (int ct = 0; ct < 2; ++ct) acc[ct] = (f32x4){0.f, 0.f, 0.f, 0.f};
        #pragma unroll
        for (int kt = 0; kt < 2; ++kt)
            #pragma unroll
            for (int ct = 0; ct < 2; ++ct)
                acc[ct] = __builtin_amdgcn_mfma_f32_16x16x32_bf16(A[kt], B[ct][kt], acc[ct], 0, 0, 0);
        #pragma unroll
        for (int ct = 0; ct < 2; ++ct) {
            int colw = w * 32 + ct * 16 + m;
            #pragma unroll
            for (int i = 0; i < 4; ++i) {
                int row = row0 + q * 4 + i;
                hB[(size_t)row * 128 + colw] = f2bf(acc[ct][i] + bias[ct]);
            }
        }
    }
}

// ---------------- dual GEMM body (used by scatter_dual + standalone) ----------------
__device__ __forceinline__ void dual_body(const unsigned short* __restrict__ hB,
                                          const unsigned short* __restrict__ Wt,
                                          const float* __restrict__ bs,
                                          const float* __restrict__ bd,
                                          unsigned short* __restrict__ fsB,
                                          unsigned short* __restrict__ fdB,
                                          unsigned short* Atile, int t0, int tstride) {
    int tid = threadIdx.x;
    int w = tid >> 6, l = tid & 63;
    int m = l & 15, q = l >> 4;
    short8 B[4][4];
    #pragma unroll
    for (int ct = 0; ct < 4; ++ct) {
        int colw = w * 64 + ct * 16 + m;
        const unsigned short* wp = Wt + colw * 128 + q * 8;
        #pragma unroll
        for (int kt = 0; kt < 4; ++kt) B[ct][kt] = *(const short8*)(wp + kt * 32);
    }
    const float* bptr = (w < 2) ? bs : bd;
    unsigned short* OUT = (w < 2) ? fsB : fdB;
    int ocb = (w * 64) & 127;
    float bias[4];
    #pragma unroll
    for (int ct = 0; ct < 4; ++ct) bias[ct] = bptr[ocb + ct * 16 + m];

    const int NT = (NN + 63) / 64;   // 782 tiles
    for (int t = t0; t < NT; t += tstride) {
        int row0 = t * 64;
        const char* gsrc = (const char*)(hB + (size_t)row0 * 128);
        #pragma unroll
        for (int c = 0; c < 4; ++c) {
            int off = c * 4096 + tid * 16;
            __builtin_amdgcn_global_load_lds((const GLOBAL_AS void*)(gsrc + off),
                                             (LDS_AS void*)((char*)Atile + off), 16, 0, 0);
        }
        __syncthreads();
        #pragma unroll
        for (int rg = 0; rg < 4; ++rg) {
            const unsigned short* ap = Atile + (rg * 16 + m) * 128 + q * 8;
            short8 A[4];
            #pragma unroll
            for (int kt = 0; kt < 4; ++kt) A[kt] = *(const short8*)(ap + kt * 32);
            f32x4 acc[4];
            #pragma unroll
            for (int ct = 0; ct < 4; ++ct) acc[ct] = (f32x4){0.f, 0.f, 0.f, 0.f};
            #pragma unroll
            for (int kt = 0; kt < 4; ++kt)
                #pragma unroll
                for (int ct = 0; ct < 4; ++ct)
                    acc[ct] = __builtin_amdgcn_mfma_f32_16x16x32_bf16(A[kt], B[ct][kt], acc[ct], 0, 0, 0);
            #pragma unroll
            for (int ct = 0; ct < 4; ++ct) {
                int colw = ocb + ct * 16 + m;
                #pragma unroll
                for (int i = 0; i < 4; ++i) {
                    int row = row0 + rg * 16 + q * 4 + i;
                    if (row < NN) OUT[(size_t)row * 128 + colw] = f2bf(acc[ct][i] + bias[ct]);
                }
            }
        }
        __syncthreads();
    }
}

// fused: CSR scatter (atomic-free) | layer-0 dual GEMM — independent, overlap them.
__global__ __launch_bounds__(256, 4) void scatter_dual_kernel(
        const int* __restrict__ src, const int* __restrict__ dst,
        const int* __restrict__ rank, const int* __restrict__ row_beg,
        const int* __restrict__ counts, const unsigned* __restrict__ cntmat,
        int* __restrict__ col, int E, int n,
        const unsigned short* __restrict__ hB, const unsigned short* __restrict__ Wt,
        const float* __restrict__ bs, const float* __restrict__ bd,
        unsigned short* __restrict__ fsB, unsigned short* __restrict__ fdB) {
    __shared__ unsigned short Atile[64 * 128];   // 16 KB (dual branch only)
    int SB = (E + n + 255) >> 8;
    if ((int)blockIdx.x < SB) {
        int i = blockIdx.x * 256 + threadIdx.x;
        if (i >= E + n) return;
        if (i < E) {
            int d = dst[i];
            int b = i >> CSH;
            unsigned pk = cntmat[(size_t)b * NPAIR + (d >> 1)];
            int off = (int)((pk >> ((unsigned)(d & 1) << 4)) & 0xffffu);
            col[row_beg[d] + off + rank[i]] = src[i];
        } else {
            int v = i - E;
            col[row_beg[v] + counts[v]] = v;
        }
        return;
    }
    dual_body(hB, Wt, bs, bd, fsB, fdB, Atile, blockIdx.x - SB, gridDim.x - SB);
}

// standalone dual (layers 1,2)
__global__ __launch_bounds__(256, 4) void dual_gemm_mfma(const unsigned short* __restrict__ hB,
                                                         const unsigned short* __restrict__ Wt,
                                                         const float* __restrict__ bs,
                                                         const float* __restrict__ bd,
                                                         unsigned short* __restrict__ fsB,
                                                         unsigned short* __restrict__ fdB) {
    __shared__ unsigned short Atile[64 * 128];
    dual_body(hB, Wt, bs, bd, fsB, fdB, Atile, blockIdx.x, gridDim.x);
}

// ---------------- fused gather attention + residual + LN + relu ----------------
// 2 dst nodes/wave, 4 feats/lane, x4 edge ILP, ONE node-pair per wave then exit.
// Lessons locked in: r1 persistent-loop -14%; r6 mid-kernel barrier -2x; r8 x8
// ILP -13% (53->60us: tripled code size, waves avg only ~2 main iters at deg~17).
// Last layer fuses graph-mean block partials (cross-half shfl + 2KB LDS stage
// AFTER the loop -- end-of-life coupling only, proven free in r8).
__global__ __launch_bounds__(256) void agg_ln_kernel(const unsigned short* __restrict__ h_in,
                                                     const unsigned short* __restrict__ fsB,
                                                     const unsigned short* __restrict__ fdB,
                                                     const int* __restrict__ row_beg,
                                                     const int* __restrict__ counts,
                                                     const int* __restrict__ col,
                                                     const float* __restrict__ attn,
                                                     const float* __restrict__ ln_g,
                                                     const float* __restrict__ ln_b,
                                                     unsigned short* __restrict__ hb_out,
                                                     float* __restrict__ hf_out,
                                                     float* __restrict__ partials, int n) {
    __shared__ float part[4][128];   // 2 KB, used only on the hf_out (last) layer
    int gwave = (blockIdx.x * blockDim.x + threadIdx.x) >> 6;
    int wid = threadIdx.x >> 6;
    int lane = threadIdx.x & 63;
    int half = lane >> 5;
    int sub = lane & 31;
    int node = gwave * 2 + half;
    if (node >= n) return;           // never taken at N=50000 (grid exact)
    int f0 = 4 * sub;
    unsigned foff = (unsigned)(f0 * 2);          // byte offset within a 256B bf16 row
    const char* fsp = (const char*)fsB;
    float4 fd4 = bfu4(*(const ushort4*)((const char*)fdB + (((unsigned)node << 8) | foff)));
    float4 h4 = bfu4(*(const ushort4*)((const char*)h_in + (((unsigned)node << 8) | foff)));
    const float4 a4 = *(const float4*)(attn + f0);
    float4 a06, a04;
    a06.x = 0.6f * a4.x; a06.y = 0.6f * a4.y; a06.z = 0.6f * a4.z; a06.w = 0.6f * a4.w;
    a04.x = 0.4f * a4.x; a04.y = 0.4f * a4.y; a04.z = 0.4f * a4.z; a04.w = 0.4f * a4.w;
    int beg = row_beg[node], end = beg + counts[node] + 1;

    float z[4];
    float4 acc[4];
    #pragma unroll
    for (int k = 0; k < 4; ++k) {
        z[k] = 0.f;
        acc[k].x = 0.f; acc[k].y = 0.f; acc[k].z = 0.f; acc[k].w = 0.f;
    }

    int j = beg;
    for (; j + 3 < end; j += 4) {
        int s0 = col[j], s1 = col[j + 1], s2 = col[j + 2], s3 = col[j + 3];
        ushort4 u0 = *(const ushort4*)(fsp + (((unsigned)s0 << 8) | foff));
        ushort4 u1 = *(const ushort4*)(fsp + (((unsigned)s1 << 8) | foff));
        ushort4 u2 = *(const ushort4*)(fsp + (((unsigned)s2 << 8) | foff));
        ushort4 u3 = *(const ushort4*)(fsp + (((unsigned)s3 << 8) | foff));
        float4 v0 = bfu4(u0), v1 = bfu4(u1), v2 = bfu4(u2), v3 = bfu4(u3);
        float p0 = edge_logit(v0, fd4, a06, a04);
        float p1 = edge_logit(v1, fd4, a06, a04);
        float p2 = edge_logit(v2, fd4, a06, a04);
        float p3 = edge_logit(v3, fd4, a06, a04);
        #pragma unroll
        for (int off = 1; off <= 4; off <<= 1) {
            p0 += __shfl_xor(p0, off); p1 += __shfl_xor(p1, off);
            p2 += __shfl_xor(p2, off); p3 += __shfl_xor(p3, off);
        }
        float w0 = __expf(p0), w1 = __expf(p1), w2 = __expf(p2), w3 = __expf(p3);
        z[0] += w0; z[1] += w1; z[2] += w2; z[3] += w3;
        acc[0].x += w0 * v0.x; acc[0].y += w0 * v0.y; acc[0].z += w0 * v0.z; acc[0].w += w0 * v0.w;
        acc[1].x += w1 * v1.x; acc[1].y += w1 * v1.y; acc[1].z += w1 * v1.z; acc[1].w += w1 * v1.w;
        acc[2].x += w2 * v2.x; acc[2].y += w2 * v2.y; acc[2].z += w2 * v2.z; acc[2].w += w2 * v2.w;
        acc[3].x += w3 * v3.x; acc[3].y += w3 * v3.y; acc[3].z += w3 * v3.z; acc[3].w += w3 * v3.w;
    }
    for (; j < end; ++j) {
        int s = col[j];
        ushort4 u = *(const ushort4*)(fsp + (((unsigned)s << 8) | foff));
        float4 v = bfu4(u);
        float p = edge_logit(v, fd4, a06, a04);
        p += __shfl_xor(p, 1);
        p += __shfl_xor(p, 2);
        p += __shfl_xor(p, 4);
        float w = __expf(p);
        z[0] += w;
        acc[0].x += w * v.x; acc[0].y += w * v.y; acc[0].z += w * v.z; acc[0].w += w * v.w;
    }
    float zT = (z[0] + z[1]) + (z[2] + z[3]);
    float axT = (acc[0].x + acc[1].x) + (acc[2].x + acc[3].x);
    float ayT = (acc[0].y + acc[1].y) + (acc[2].y + acc[3].y);
    float azT = (acc[0].z + acc[1].z) + (acc[2].z + acc[3].z);
    float awT = (acc[0].w + acc[1].w) + (acc[2].w + acc[3].w);
    float inv = 1.0f / zT;
    float x0 = 2.f * h4.x + axT * inv;  // h + (aggr + h)
    float x1 = 2.f * h4.y + ayT * inv;
    float x2 = 2.f * h4.z + azT * inv;
    float x3 = 2.f * h4.w + awT * inv;
    float s = (x0 + x1) + (x2 + x3);
    #pragma unroll
    for (int off = 1; off <= 16; off <<= 1) s += __shfl_xor(s, off);
    float mean = s * (1.f / 128.f);
    float d0 = x0 - mean, d1 = x1 - mean, d2 = x2 - mean, d3 = x3 - mean;
    float v = (d0 * d0 + d1 * d1) + (d2 * d2 + d3 * d3);
    #pragma unroll
    for (int off = 1; off <= 16; off <<= 1) v += __shfl_xor(v, off);
    float rstd = rsqrtf(v * (1.f / 128.f) + 1e-5f);
    float4 g4 = *(const float4*)(ln_g + f0);
    float4 bb4 = *(const float4*)(ln_b + f0);
    float4 o;
    o.x = fmaxf(d0 * rstd * g4.x + bb4.x, 0.f);
    o.y = fmaxf(d1 * rstd * g4.y + bb4.y, 0.f);
    o.z = fmaxf(d2 * rstd * g4.z + bb4.z, 0.f);
    o.w = fmaxf(d3 * rstd * g4.w + bb4.w, 0.f);
    if (hf_out) {
        *(float4*)((char*)hf_out + (((unsigned)node << 9) | (unsigned)(f0 * 4))) = o;
        // fused graph-mean partial: sum this block's 8 nodes. Cross-half add first
        // (lane^32 pairs the wave's two nodes), then per-wave LDS row, one barrier,
        // 128 threads emit the block partial. No atomics, no in-loop barriers.
        float4 t = o;
        t.x += __shfl_xor(t.x, 32);
        t.y += __shfl_xor(t.y, 32);
        t.z += __shfl_xor(t.z, 32);
        t.w += __shfl_xor(t.w, 32);
        if (half == 0) *(float4*)(&part[wid][f0]) = t;
        __syncthreads();
        int tt = threadIdx.x;
        if (tt < 128) {
            partials[(size_t)blockIdx.x * 128 + tt] =
                (part[0][tt] + part[1][tt]) + (part[2][tt] + part[3][tt]);
        }
    } else {
        ushort4 ob;
        ob.x = f2bf(o.x); ob.y = f2bf(o.y); ob.z = f2bf(o.z); ob.w = f2bf(o.w);
        *(ushort4*)((char*)hb_out + (((unsigned)node << 8) | foff)) = ob;
    }
}

// ---------------- graph mean finish: 6250 partials -> 256 -> 1 (r7 lesson: a
// single-block reduction of 3.2MB runs at 1-CU bandwidth = 223us; keep 2 stages) ----
__global__ __launch_bounds__(128) void mean_r1_kernel(const float* __restrict__ partials,
                                                      float* __restrict__ partials2, int nb) {
    int c = threadIdx.x;
    float acc = 0.f;
    for (int r = blockIdx.x; r < nb; r += gridDim.x)
        acc += partials[(size_t)r * 128 + c];
    partials2[blockIdx.x * 128 + c] = acc;
}

__global__ __launch_bounds__(1024) void mean2_kernel(const float* __restrict__ partials,
                                                     float* __restrict__ out, int nb, int n) {
    __shared__ float smem[8][128];
    int c = threadIdx.x & 127;
    int g = threadIdx.x >> 7;  // 0..7
    float acc = 0.f;
    for (int r = g; r < nb; r += 8)
        acc += partials[r * 128 + c];
    smem[g][c] = acc;
    __syncthreads();
    if (threadIdx.x < 128) {
        float s = 0.f;
        #pragma unroll
        for (int k = 0; k < 8; ++k) s += smem[k][c];
        out[c] = s * (1.f / n);
    }
}

extern "C" void kernel_launch(void* const* d_in, const int* in_sizes, int n_in,
                              void* d_out, int out_size, void* d_ws, size_t ws_size,
                              hipStream_t stream) {
    const float* node_feats = (const float*)d_in[0];
    const int* src = (const int*)d_in[1];
    const int* dst = (const int*)d_in[2];
    const float* W_in = (const float*)d_in[3];
    const float* b_in = (const float*)d_in[4];
    const float* W_src = (const float*)d_in[5];
    const float* b_src = (const float*)d_in[6];
    const float* W_dst = (const float*)d_in[7];
    const float* b_dst = (const float*)d_in[8];
    const float* attn = (const float*)d_in[9];
    const float* ln_g = (const float*)d_in[10];
    const float* ln_b = (const float*)d_in[11];
    float* out = (float*)d_out;

    const int N = NN;
    const int E = in_sizes[1];
    const int HB = (E + CHUNK - 1) >> CSH;   // 98 hist blocks @ E=800K

    // workspace layout
    unsigned short* fsB = (unsigned short*)d_ws;      // N*128 bf16
    unsigned short* fdB = fsB + (size_t)N * 128;      // N*128 bf16
    unsigned short* hB = fdB + (size_t)N * 128;       // N*128 bf16
    unsigned short* WtL = hB + (size_t)N * 128;       // 3*256*128 bf16
    unsigned short* WtIn = WtL + 3 * 32768;           // 128*64 bf16 (unused, layout kept)
    int* counts = (int*)(WtIn + 8192);                // N
    int* total = counts + N;                          // 1 (memset)
    int* row_beg = total + 1;                         // N
    int* rankb = row_beg + N;                         // E
    int* colb = rankb + E;                            // E+N
    unsigned* cntmat = (unsigned*)(colb + (E + N));   // HB*NPAIR u32 (~9.8MB)
    float* partials = (float*)(cntmat + (size_t)HB * NPAIR);  // 6250*128 f32 (3.2MB)
    float* partials2 = partials + (size_t)6250 * 128;         // 256*128 f32

    const int NT = (N + 63) / 64;   // 782 dual tiles
    const int AB = (N + 7) / 8;     // 6250 agg blocks (N % 8 == 0: every wave full)

    hipMemsetAsync(total, 0, sizeof(int), stream);

    // --- pass 1: block-local LDS hist (no device atomics) ---
    hist_kernel<<<HB, 256, 0, stream>>>(dst, cntmat, rankb, E);

    // --- pass 2: block-prefix + alloc | WtL convert | in_proj ---
    const int PB = (NPAIR + 255) / 256;   // 98
    prep2_kernel<<<PB + 384 + 512, 256, 0, stream>>>(cntmat, HB, counts, row_beg, total,
                                                     W_src, W_dst, WtL,
                                                     node_feats, W_in, b_in, hB);

    // --- pass 3: scatter | layer-0 dual GEMM ---
    int SB = (E + N + 255) / 256;
    scatter_dual_kernel<<<SB + NT, 256, 0, stream>>>(src, dst, rankb, row_beg,
                                                     counts, cntmat, colb, E, N,
                                                     hB, WtL, b_src, b_dst, fsB, fdB);

    // --- 3 GATv2 layers ---
    for (int l = 0; l < 3; ++l) {
        int last = (l == 2);
        if (l > 0)
            dual_gemm_mfma<<<NT, 256, 0, stream>>>(hB, WtL + (size_t)l * 32768,
                                                   b_src + l * 128, b_dst + l * 128,
                                                   fsB, fdB);
        agg_ln_kernel<<<AB, 256, 0, stream>>>(hB, fsB, fdB, row_beg, counts, colb,
                                              attn + l * 128, ln_g + l * 128,
                                              ln_b + l * 128,
                                              last ? nullptr : hB,
                                              last ? (out + 128) : nullptr,
                                              partials, N);
    }

    // --- graph mean finish into out[0:128] (two-stage over block partials) ---
    mean_r1_kernel<<<256, 128, 0, stream>>>(partials, partials2, AB);
    mean2_kernel<<<1, 1024, 0, stream>>>(partials2, out, 256, N);
}

// Round 10
// 346.954 us; speedup vs baseline: 1.6431x; 1.0443x over previous
//
#include <hip/hip_runtime.h>
#include <hip/hip_bf16.h>

#define NN 50000
#define NPAIR 25000     // packed 2x16-bit LDS counters: 25000 u32 = 100KB (<160KB)
#define CSH 13          // hist chunk = 8192 edges/block
#define CHUNK (1 << CSH)

typedef short short8 __attribute__((ext_vector_type(8)));
typedef float f32x4 __attribute__((ext_vector_type(4)));

#define GLOBAL_AS __attribute__((address_space(1)))
#define LDS_AS __attribute__((address_space(3)))

__device__ __forceinline__ unsigned short f2bf(float f) {
    unsigned int b = __float_as_uint(f);
    unsigned int r = (b + 0x7FFFu + ((b >> 16) & 1u)) >> 16;   // RNE
    return (unsigned short)r;
}
__device__ __forceinline__ float bf2f(unsigned short u) {
    return __uint_as_float((unsigned int)u << 16);
}
__device__ __forceinline__ float4 bfu4(ushort4 u) {
    float4 v;
    v.x = bf2f(u.x); v.y = bf2f(u.y); v.z = bf2f(u.z); v.w = bf2f(u.w);
    return v;
}
// lrelu(e)*a folded: lrelu(e) = 0.6e + 0.4|e| (slope 0.2); abs is a free VOP3 mod
__device__ __forceinline__ float edge_logit(float4 v, float4 fd4, float4 a06, float4 a04) {
    float e0 = v.x + fd4.x, e1 = v.y + fd4.y, e2 = v.z + fd4.z, e3 = v.w + fd4.w;
    return e0 * a06.x + fabsf(e0) * a04.x + e1 * a06.y + fabsf(e1) * a04.y
         + e2 * a06.z + fabsf(e2) * a04.z + e3 * a06.w + fabsf(e3) * a04.w;
}

// ---------------- pass 1: block-local full-range LDS histogram (r5-proven) ----------------
__global__ __launch_bounds__(256) void hist_kernel(const int* __restrict__ dst,
                                                   unsigned* __restrict__ cntmat,
                                                   int* __restrict__ rank, int E) {
    __shared__ unsigned pc[NPAIR];
    int b = blockIdx.x, tid = threadIdx.x;
    for (int k = tid; k < NPAIR; k += 256) pc[k] = 0;
    __syncthreads();
    int beg = b << CSH;
    int end = beg + CHUNK; if (end > E) end = E;
    for (int i = beg + tid; i < end; i += 256) {
        int d = dst[i];
        unsigned sh = (unsigned)(d & 1) << 4;
        unsigned old = atomicAdd(&pc[d >> 1], 1u << sh);
        rank[i] = (int)((old >> sh) & 0xffffu);
    }
    __syncthreads();
    unsigned* o = cntmat + (size_t)b * NPAIR;
    for (int k = tid; k < NPAIR; k += 256) o[k] = pc[k];
}

// ---------------- pass 2 fused: block-prefix + alloc | WtL convert | in_proj ----------------
__global__ __launch_bounds__(256, 4) void prep2_kernel(
        unsigned* __restrict__ cntmat, int HB,
        int* __restrict__ counts, int* __restrict__ row_beg, int* total,
        const float* __restrict__ Ws, const float* __restrict__ Wd,
        unsigned short* __restrict__ WtL,
        const float* __restrict__ x, const float* __restrict__ Win,
        const float* __restrict__ bin, unsigned short* __restrict__ hB) {
    const int PB = (NPAIR + 255) / 256;   // 98
    int blk = blockIdx.x, tid = threadIdx.x;
    if (blk < PB) {
        int p = blk * 256 + tid;
        unsigned run = 0;
        if (p < NPAIR) {
            size_t idx = p;
            #pragma unroll 4
            for (int b = 0; b < HB; ++b, idx += NPAIR) {
                unsigned c = cntmat[idx];
                cntmat[idx] = run;          // exclusive prefix for (block b, pair p)
                run += c;
            }
        }
        int c0 = (int)(run & 0xffffu), c1 = (int)(run >> 16);
        int lane = tid & 63;
        int len = (p < NPAIR) ? (c0 + c1 + 2) : 0;   // both nodes + 2 self loops
        int pscan = len;
        #pragma unroll
        for (int off = 1; off < 64; off <<= 1) {
            int t = __shfl_up(pscan, off);
            if (lane >= off) pscan += t;
        }
        int tot = __shfl(pscan, 63);
        int base = 0;
        if (lane == 63) base = atomicAdd(total, tot);
        base = __shfl(base, 63);
        if (p < NPAIR) {
            int rb = base + pscan - len;
            counts[2 * p] = c0;
            counts[2 * p + 1] = c1;
            row_beg[2 * p] = rb;
            row_beg[2 * p + 1] = rb + c0 + 1;
        }
        return;
    }
    int w = tid >> 6, l = tid & 63;
    int m = l & 15, q = l >> 4;
    if (blk < PB + 384) {
        // --- WtL bf16 transpose-convert (3 layers x [256 cols][128 k]) ---
        int e = (blk - PB) * 256 + tid;  // 0..98303
        int ll = e >> 15;
        int r = e & 32767;
        int colc = r >> 7;
        int k = r & 127;
        float v = (colc < 128) ? Ws[ll * 16384 + k * 128 + colc]
                               : Wd[ll * 16384 + k * 128 + (colc - 128)];
        WtL[ll * 32768 + colc * 128 + k] = f2bf(v);
        return;
    }
    // --- in_proj MFMA: x[N,64] @ W_in[64,128] + b -> hB bf16 (W_in converted inline) ---
    int blk0 = blk - PB - 384;           // 0..511
    short8 B[2][2];
    #pragma unroll
    for (int ct = 0; ct < 2; ++ct) {
        int colw = w * 32 + ct * 16 + m;
        #pragma unroll
        for (int kt = 0; kt < 2; ++kt) {
            short8 a;
            #pragma unroll
            for (int jj = 0; jj < 8; ++jj)
                a[jj] = (short)f2bf(Win[(kt * 32 + q * 8 + jj) * 128 + colw]);
            B[ct][kt] = a;
        }
    }
    float bias[2];
    #pragma unroll
    for (int ct = 0; ct < 2; ++ct) bias[ct] = bin[w * 32 + ct * 16 + m];
    for (int rg = blk0; rg < NN / 16; rg += 512) {
        int row0 = rg * 16;
        const float* ap = x + (size_t)(row0 + m) * 64 + q * 8;
        short8 A[2];
        #pragma unroll
        for (int kt = 0; kt < 2; ++kt) {
            float4 f0 = *(const float4*)(ap + kt * 32);
            float4 f1 = *(const float4*)(ap + kt * 32 + 4);
            short8 a;
            a[0] = (short)f2bf(f0.x); a[1] = (short)f2bf(f0.y);
            a[2] = (short)f2bf(f0.z); a[3] = (short)f2bf(f0.w);
            a[4] = (short)f2bf(f1.x); a[5] = (short)f2bf(f1.y);
            a[6] = (short)f2bf(f1.z); a[7] = (short)f2bf(f1.w);
            A[kt] = a;
        }
        f32x4 acc[2];
        #pragma unroll
        for (int ct = 0; ct < 2; ++ct) acc[ct] = (f32x4){0.f, 0.f, 0.f, 0.f};
        #pragma unroll
        for (int kt = 0; kt < 2; ++kt)
            #pragma unroll
            for (int ct = 0; ct < 2; ++ct)
                acc[ct] = __builtin_amdgcn_mfma_f32_16x16x32_bf16(A[kt], B[ct][kt], acc[ct], 0, 0, 0);
        #pragma unroll
        for (int ct = 0; ct < 2; ++ct) {
            int colw = w * 32 + ct * 16 + m;
            #pragma unroll
            for (int i = 0; i < 4; ++i) {
                int row = row0 + q * 4 + i;
                hB[(size_t)row * 128 + colw] = f2bf(acc[ct][i] + bias[ct]);
            }
        }
    }
}

// ---------------- dual GEMM body (used by scatter_dual + standalone) ----------------
__device__ __forceinline__ void dual_body(const unsigned short* __restrict__ hB,
                                          const unsigned short* __restrict__ Wt,
                                          const float* __restrict__ bs,
                                          const float* __restrict__ bd,
                                          unsigned short* __restrict__ fsB,
                                          unsigned short* __restrict__ fdB,
                                          unsigned short* Atile, int t0, int tstride) {
    int tid = threadIdx.x;
    int w = tid >> 6, l = tid & 63;
    int m = l & 15, q = l >> 4;
    short8 B[4][4];
    #pragma unroll
    for (int ct = 0; ct < 4; ++ct) {
        int colw = w * 64 + ct * 16 + m;
        const unsigned short* wp = Wt + colw * 128 + q * 8;
        #pragma unroll
        for (int kt = 0; kt < 4; ++kt) B[ct][kt] = *(const short8*)(wp + kt * 32);
    }
    const float* bptr = (w < 2) ? bs : bd;
    unsigned short* OUT = (w < 2) ? fsB : fdB;
    int ocb = (w * 64) & 127;
    float bias[4];
    #pragma unroll
    for (int ct = 0; ct < 4; ++ct) bias[ct] = bptr[ocb + ct * 16 + m];

    const int NT = (NN + 63) / 64;   // 782 tiles
    for (int t = t0; t < NT; t += tstride) {
        int row0 = t * 64;
        const char* gsrc = (const char*)(hB + (size_t)row0 * 128);
        #pragma unroll
        for (int c = 0; c < 4; ++c) {
            int off = c * 4096 + tid * 16;
            __builtin_amdgcn_global_load_lds((const GLOBAL_AS void*)(gsrc + off),
                                             (LDS_AS void*)((char*)Atile + off), 16, 0, 0);
        }
        __syncthreads();
        #pragma unroll
        for (int rg = 0; rg < 4; ++rg) {
            const unsigned short* ap = Atile + (rg * 16 + m) * 128 + q * 8;
            short8 A[4];
            #pragma unroll
            for (int kt = 0; kt < 4; ++kt) A[kt] = *(const short8*)(ap + kt * 32);
            f32x4 acc[4];
            #pragma unroll
            for (int ct = 0; ct < 4; ++ct) acc[ct] = (f32x4){0.f, 0.f, 0.f, 0.f};
            #pragma unroll
            for (int kt = 0; kt < 4; ++kt)
                #pragma unroll
                for (int ct = 0; ct < 4; ++ct)
                    acc[ct] = __builtin_amdgcn_mfma_f32_16x16x32_bf16(A[kt], B[ct][kt], acc[ct], 0, 0, 0);
            #pragma unroll
            for (int ct = 0; ct < 4; ++ct) {
                int colw = ocb + ct * 16 + m;
                #pragma unroll
                for (int i = 0; i < 4; ++i) {
                    int row = row0 + rg * 16 + q * 4 + i;
                    if (row < NN) OUT[(size_t)row * 128 + colw] = f2bf(acc[ct][i] + bias[ct]);
                }
            }
        }
        __syncthreads();
    }
}

// fused: layer-0 dual GEMM | CSR scatter. Dual tiles get blockIdx 0..NT-1 so the
// long-pole GEMM blocks dispatch FIRST; the ~3320 short scatter blocks backfill.
__global__ __launch_bounds__(256, 4) void scatter_dual_kernel(
        const int* __restrict__ src, const int* __restrict__ dst,
        const int* __restrict__ rank, const int* __restrict__ row_beg,
        const int* __restrict__ counts, const unsigned* __restrict__ cntmat,
        int* __restrict__ col, int E, int n,
        const unsigned short* __restrict__ hB, const unsigned short* __restrict__ Wt,
        const float* __restrict__ bs, const float* __restrict__ bd,
        unsigned short* __restrict__ fsB, unsigned short* __restrict__ fdB) {
    __shared__ unsigned short Atile[64 * 128];   // 16 KB (dual branch only)
    const int NT = (NN + 63) / 64;
    if ((int)blockIdx.x < NT) {
        dual_body(hB, Wt, bs, bd, fsB, fdB, Atile, blockIdx.x, NT);
        return;
    }
    int i = (blockIdx.x - NT) * 256 + threadIdx.x;
    if (i >= E + n) return;
    if (i < E) {
        int d = dst[i];
        int b = i >> CSH;
        unsigned pk = cntmat[(size_t)b * NPAIR + (d >> 1)];
        int off = (int)((pk >> ((unsigned)(d & 1) << 4)) & 0xffffu);
        col[row_beg[d] + off + rank[i]] = src[i];
    } else {
        int v = i - E;
        col[row_beg[v] + counts[v]] = v;
    }
}

// standalone dual (layers 1,2)
__global__ __launch_bounds__(256, 4) void dual_gemm_mfma(const unsigned short* __restrict__ hB,
                                                         const unsigned short* __restrict__ Wt,
                                                         const float* __restrict__ bs,
                                                         const float* __restrict__ bd,
                                                         unsigned short* __restrict__ fsB,
                                                         unsigned short* __restrict__ fdB) {
    __shared__ unsigned short Atile[64 * 128];
    dual_body(hB, Wt, bs, bd, fsB, fdB, Atile, blockIdx.x, gridDim.x);
}

// ---------------- fused gather attention + residual + LN + relu ----------------
// 2 dst nodes/wave, 4 feats/lane, x4 edge ILP, ONE node-pair per wave then exit.
// Lessons locked in: r1 persistent-loop -14%; r6 mid-kernel barrier -2x; r8 x8
// ILP -13%; r9 mean-epilogue compiled into all layers taxed l0/l1 by ~4us each
// (VGPR 40->44, LDS 0->2KB) -> template-split so only LAST carries it.
template <bool LAST>
__global__ __launch_bounds__(256) void agg_ln_kernel(const unsigned short* __restrict__ h_in,
                                                     const unsigned short* __restrict__ fsB,
                                                     const unsigned short* __restrict__ fdB,
                                                     const int* __restrict__ row_beg,
                                                     const int* __restrict__ counts,
                                                     const int* __restrict__ col,
                                                     const float* __restrict__ attn,
                                                     const float* __restrict__ ln_g,
                                                     const float* __restrict__ ln_b,
                                                     unsigned short* __restrict__ hb_out,
                                                     float* __restrict__ hf_out,
                                                     float* __restrict__ partials, int n) {
    int gwave = (blockIdx.x * blockDim.x + threadIdx.x) >> 6;
    int wid = threadIdx.x >> 6;
    int lane = threadIdx.x & 63;
    int half = lane >> 5;
    int sub = lane & 31;
    int node = gwave * 2 + half;
    if (node >= n) return;           // never taken at N=50000 (grid exact)
    int f0 = 4 * sub;
    unsigned foff = (unsigned)(f0 * 2);          // byte offset within a 256B bf16 row
    const char* fsp = (const char*)fsB;
    float4 fd4 = bfu4(*(const ushort4*)((const char*)fdB + (((unsigned)node << 8) | foff)));
    float4 h4 = bfu4(*(const ushort4*)((const char*)h_in + (((unsigned)node << 8) | foff)));
    const float4 a4 = *(const float4*)(attn + f0);
    float4 a06, a04;
    a06.x = 0.6f * a4.x; a06.y = 0.6f * a4.y; a06.z = 0.6f * a4.z; a06.w = 0.6f * a4.w;
    a04.x = 0.4f * a4.x; a04.y = 0.4f * a4.y; a04.z = 0.4f * a4.z; a04.w = 0.4f * a4.w;
    int beg = row_beg[node], end = beg + counts[node] + 1;

    float z[4];
    float4 acc[4];
    #pragma unroll
    for (int k = 0; k < 4; ++k) {
        z[k] = 0.f;
        acc[k].x = 0.f; acc[k].y = 0.f; acc[k].z = 0.f; acc[k].w = 0.f;
    }

    int j = beg;
    for (; j + 3 < end; j += 4) {
        int s0 = col[j], s1 = col[j + 1], s2 = col[j + 2], s3 = col[j + 3];
        ushort4 u0 = *(const ushort4*)(fsp + (((unsigned)s0 << 8) | foff));
        ushort4 u1 = *(const ushort4*)(fsp + (((unsigned)s1 << 8) | foff));
        ushort4 u2 = *(const ushort4*)(fsp + (((unsigned)s2 << 8) | foff));
        ushort4 u3 = *(const ushort4*)(fsp + (((unsigned)s3 << 8) | foff));
        float4 v0 = bfu4(u0), v1 = bfu4(u1), v2 = bfu4(u2), v3 = bfu4(u3);
        float p0 = edge_logit(v0, fd4, a06, a04);
        float p1 = edge_logit(v1, fd4, a06, a04);
        float p2 = edge_logit(v2, fd4, a06, a04);
        float p3 = edge_logit(v3, fd4, a06, a04);
        #pragma unroll
        for (int off = 1; off <= 4; off <<= 1) {
            p0 += __shfl_xor(p0, off); p1 += __shfl_xor(p1, off);
            p2 += __shfl_xor(p2, off); p3 += __shfl_xor(p3, off);
        }
        float w0 = __expf(p0), w1 = __expf(p1), w2 = __expf(p2), w3 = __expf(p3);
        z[0] += w0; z[1] += w1; z[2] += w2; z[3] += w3;
        acc[0].x += w0 * v0.x; acc[0].y += w0 * v0.y; acc[0].z += w0 * v0.z; acc[0].w += w0 * v0.w;
        acc[1].x += w1 * v1.x; acc[1].y += w1 * v1.y; acc[1].z += w1 * v1.z; acc[1].w += w1 * v1.w;
        acc[2].x += w2 * v2.x; acc[2].y += w2 * v2.y; acc[2].z += w2 * v2.z; acc[2].w += w2 * v2.w;
        acc[3].x += w3 * v3.x; acc[3].y += w3 * v3.y; acc[3].z += w3 * v3.z; acc[3].w += w3 * v3.w;
    }
    for (; j < end; ++j) {
        int s = col[j];
        ushort4 u = *(const ushort4*)(fsp + (((unsigned)s << 8) | foff));
        float4 v = bfu4(u);
        float p = edge_logit(v, fd4, a06, a04);
        p += __shfl_xor(p, 1);
        p += __shfl_xor(p, 2);
        p += __shfl_xor(p, 4);
        float w = __expf(p);
        z[0] += w;
        acc[0].x += w * v.x; acc[0].y += w * v.y; acc[0].z += w * v.z; acc[0].w += w * v.w;
    }
    float zT = (z[0] + z[1]) + (z[2] + z[3]);
    float axT = (acc[0].x + acc[1].x) + (acc[2].x + acc[3].x);
    float ayT = (acc[0].y + acc[1].y) + (acc[2].y + acc[3].y);
    float azT = (acc[0].z + acc[1].z) + (acc[2].z + acc[3].z);
    float awT = (acc[0].w + acc[1].w) + (acc[2].w + acc[3].w);
    float inv = 1.0f / zT;
    float x0 = 2.f * h4.x + axT * inv;  // h + (aggr + h)
    float x1 = 2.f * h4.y + ayT * inv;
    float x2 = 2.f * h4.z + azT * inv;
    float x3 = 2.f * h4.w + awT * inv;
    float s = (x0 + x1) + (x2 + x3);
    #pragma unroll
    for (int off = 1; off <= 16; off <<= 1) s += __shfl_xor(s, off);
    float mean = s * (1.f / 128.f);
    float d0 = x0 - mean, d1 = x1 - mean, d2 = x2 - mean, d3 = x3 - mean;
    float v = (d0 * d0 + d1 * d1) + (d2 * d2 + d3 * d3);
    #pragma unroll
    for (int off = 1; off <= 16; off <<= 1) v += __shfl_xor(v, off);
    float rstd = rsqrtf(v * (1.f / 128.f) + 1e-5f);
    float4 g4 = *(const float4*)(ln_g + f0);
    float4 bb4 = *(const float4*)(ln_b + f0);
    float4 o;
    o.x = fmaxf(d0 * rstd * g4.x + bb4.x, 0.f);
    o.y = fmaxf(d1 * rstd * g4.y + bb4.y, 0.f);
    o.z = fmaxf(d2 * rstd * g4.z + bb4.z, 0.f);
    o.w = fmaxf(d3 * rstd * g4.w + bb4.w, 0.f);
    if constexpr (LAST) {
        *(float4*)((char*)hf_out + (((unsigned)node << 9) | (unsigned)(f0 * 4))) = o;
        // fused graph-mean partial: sum this block's 8 nodes. Cross-half add first
        // (lane^32 pairs the wave's two nodes), then per-wave LDS row, one barrier,
        // 128 threads emit the block partial. No atomics, no in-loop barriers.
        __shared__ float part[4][128];   // 2 KB, LAST instantiation only
        float4 t = o;
        t.x += __shfl_xor(t.x, 32);
        t.y += __shfl_xor(t.y, 32);
        t.z += __shfl_xor(t.z, 32);
        t.w += __shfl_xor(t.w, 32);
        if (half == 0) *(float4*)(&part[wid][f0]) = t;
        __syncthreads();
        int tt = threadIdx.x;
        if (tt < 128) {
            partials[(size_t)blockIdx.x * 128 + tt] =
                (part[0][tt] + part[1][tt]) + (part[2][tt] + part[3][tt]);
        }
    } else {
        ushort4 ob;
        ob.x = f2bf(o.x); ob.y = f2bf(o.y); ob.z = f2bf(o.z); ob.w = f2bf(o.w);
        *(ushort4*)((char*)hb_out + (((unsigned)node << 8) | foff)) = ob;
    }
}

// ---------------- graph mean finish: 6250 partials -> 256 -> 1 (r7 lesson: a
// single-block reduction of 3.2MB runs at 1-CU bandwidth = 223us; keep 2 stages) ----
__global__ __launch_bounds__(128) void mean_r1_kernel(const float* __restrict__ partials,
                                                      float* __restrict__ partials2, int nb) {
    int c = threadIdx.x;
    float acc = 0.f;
    for (int r = blockIdx.x; r < nb; r += gridDim.x)
        acc += partials[(size_t)r * 128 + c];
    partials2[blockIdx.x * 128 + c] = acc;
}

__global__ __launch_bounds__(1024) void mean2_kernel(const float* __restrict__ partials,
                                                     float* __restrict__ out, int nb, int n) {
    __shared__ float smem[8][128];
    int c = threadIdx.x & 127;
    int g = threadIdx.x >> 7;  // 0..7
    float acc = 0.f;
    for (int r = g; r < nb; r += 8)
        acc += partials[r * 128 + c];
    smem[g][c] = acc;
    __syncthreads();
    if (threadIdx.x < 128) {
        float s = 0.f;
        #pragma unroll
        for (int k = 0; k < 8; ++k) s += smem[k][c];
        out[c] = s * (1.f / n);
    }
}

extern "C" void kernel_launch(void* const* d_in, const int* in_sizes, int n_in,
                              void* d_out, int out_size, void* d_ws, size_t ws_size,
                              hipStream_t stream) {
    const float* node_feats = (const float*)d_in[0];
    const int* src = (const int*)d_in[1];
    const int* dst = (const int*)d_in[2];
    const float* W_in = (const float*)d_in[3];
    const float* b_in = (const float*)d_in[4];
    const float* W_src = (const float*)d_in[5];
    const float* b_src = (const float*)d_in[6];
    const float* W_dst = (const float*)d_in[7];
    const float* b_dst = (const float*)d_in[8];
    const float* attn = (const float*)d_in[9];
    const float* ln_g = (const float*)d_in[10];
    const float* ln_b = (const float*)d_in[11];
    float* out = (float*)d_out;

    const int N = NN;
    const int E = in_sizes[1];
    const int HB = (E + CHUNK - 1) >> CSH;   // 98 hist blocks @ E=800K

    // workspace layout
    unsigned short* fsB = (unsigned short*)d_ws;      // N*128 bf16
    unsigned short* fdB = fsB + (size_t)N * 128;      // N*128 bf16
    unsigned short* hB = fdB + (size_t)N * 128;       // N*128 bf16
    unsigned short* WtL = hB + (size_t)N * 128;       // 3*256*128 bf16
    unsigned short* WtIn = WtL + 3 * 32768;           // 128*64 bf16 (unused, layout kept)
    int* counts = (int*)(WtIn + 8192);                // N
    int* total = counts + N;                          // 1 (memset)
    int* row_beg = total + 1;                         // N
    int* rankb = row_beg + N;                         // E
    int* colb = rankb + E;                            // E+N
    unsigned* cntmat = (unsigned*)(colb + (E + N));   // HB*NPAIR u32 (~9.8MB)
    float* partials = (float*)(cntmat + (size_t)HB * NPAIR);  // 6250*128 f32 (3.2MB)
    float* partials2 = partials + (size_t)6250 * 128;         // 256*128 f32

    const int NT = (N + 63) / 64;   // 782 dual tiles
    const int AB = (N + 7) / 8;     // 6250 agg blocks (N % 8 == 0: every wave full)

    hipMemsetAsync(total, 0, sizeof(int), stream);

    // --- pass 1: block-local LDS hist (no device atomics) ---
    hist_kernel<<<HB, 256, 0, stream>>>(dst, cntmat, rankb, E);

    // --- pass 2: block-prefix + alloc | WtL convert | in_proj ---
    const int PB = (NPAIR + 255) / 256;   // 98
    prep2_kernel<<<PB + 384 + 512, 256, 0, stream>>>(cntmat, HB, counts, row_beg, total,
                                                     W_src, W_dst, WtL,
                                                     node_feats, W_in, b_in, hB);

    // --- pass 3: layer-0 dual GEMM (blocks first) | scatter ---
    int SB = (E + N + 255) / 256;
    scatter_dual_kernel<<<NT + SB, 256, 0, stream>>>(src, dst, rankb, row_beg,
                                                     counts, cntmat, colb, E, N,
                                                     hB, WtL, b_src, b_dst, fsB, fdB);

    // --- 3 GATv2 layers ---
    for (int l = 0; l < 3; ++l) {
        if (l > 0)
            dual_gemm_mfma<<<NT, 256, 0, stream>>>(hB, WtL + (size_t)l * 32768,
                                                   b_src + l * 128, b_dst + l * 128,
                                                   fsB, fdB);
        if (l < 2)
            agg_ln_kernel<false><<<AB, 256, 0, stream>>>(hB, fsB, fdB, row_beg, counts, colb,
                                                         attn + l * 128, ln_g + l * 128,
                                                         ln_b + l * 128, hB, nullptr,
                                                         partials, N);
        else
            agg_ln_kernel<true><<<AB, 256, 0, stream>>>(hB, fsB, fdB, row_beg, counts, colb,
                                                        attn + l * 128, ln_g + l * 128,
                                                        ln_b + l * 128, nullptr, out + 128,
                                                        partials, N);
    }

    // --- graph mean finish into out[0:128] (two-stage over block partials) ---
    mean_r1_kernel<<<256, 128, 0, stream>>>(partials, partials2, AB);
    mean2_kernel<<<1, 1024, 0, stream>>>(partials2, out, 256, N);
}

// Round 11
// 340.288 us; speedup vs baseline: 1.6753x; 1.0196x over previous
//
#include <hip/hip_runtime.h>
#include <hip/hip_bf16.h>

#define NN 50000
#define NPAIR 25000     // packed 2x16-bit LDS counters: 25000 u32 = 100KB (<160KB)
#define CSH 13          // hist chunk = 8192 edges/block
#define CHUNK (1 << CSH)

typedef short short8 __attribute__((ext_vector_type(8)));
typedef float f32x4 __attribute__((ext_vector_type(4)));

#define GLOBAL_AS __attribute__((address_space(1)))
#define LDS_AS __attribute__((address_space(3)))

__device__ __forceinline__ unsigned short f2bf(float f) {
    unsigned int b = __float_as_uint(f);
    unsigned int r = (b + 0x7FFFu + ((b >> 16) & 1u)) >> 16;   // RNE
    return (unsigned short)r;
}
__device__ __forceinline__ float bf2f(unsigned short u) {
    return __uint_as_float((unsigned int)u << 16);
}
__device__ __forceinline__ float4 bfu4(ushort4 u) {
    float4 v;
    v.x = bf2f(u.x); v.y = bf2f(u.y); v.z = bf2f(u.z); v.w = bf2f(u.w);
    return v;
}
// lrelu(e)*a folded: lrelu(e) = 0.6e + 0.4|e| (slope 0.2); abs is a free VOP3 mod
__device__ __forceinline__ float edge_logit(float4 v, float4 fd4, float4 a06, float4 a04) {
    float e0 = v.x + fd4.x, e1 = v.y + fd4.y, e2 = v.z + fd4.z, e3 = v.w + fd4.w;
    return e0 * a06.x + fabsf(e0) * a04.x + e1 * a06.y + fabsf(e1) * a04.y
         + e2 * a06.z + fabsf(e2) * a04.z + e3 * a06.w + fabsf(e3) * a04.w;
}

// ---------------- pass 1: block-local full-range LDS histogram (r5-proven) ----------------
// r11: also zeroes `total` (block 0) so the standalone memset launch is deleted.
__global__ __launch_bounds__(256) void hist_kernel(const int* __restrict__ dst,
                                                   unsigned* __restrict__ cntmat,
                                                   int* __restrict__ rank, int* total, int E) {
    __shared__ unsigned pc[NPAIR];
    int b = blockIdx.x, tid = threadIdx.x;
    if (b == 0 && tid == 0) *total = 0;   // used first in prep2 (next dispatch) — safe
    for (int k = tid; k < NPAIR; k += 256) pc[k] = 0;
    __syncthreads();
    int beg = b << CSH;
    int end = beg + CHUNK; if (end > E) end = E;
    for (int i = beg + tid; i < end; i += 256) {
        int d = dst[i];
        unsigned sh = (unsigned)(d & 1) << 4;
        unsigned old = atomicAdd(&pc[d >> 1], 1u << sh);
        rank[i] = (int)((old >> sh) & 0xffffu);
    }
    __syncthreads();
    unsigned* o = cntmat + (size_t)b * NPAIR;
    for (int k = tid; k < NPAIR; k += 256) o[k] = pc[k];
}

// ---------------- pass 2 fused: block-prefix + alloc | WtL convert | in_proj ----------------
__global__ __launch_bounds__(256, 4) void prep2_kernel(
        unsigned* __restrict__ cntmat, int HB,
        int* __restrict__ counts, int* __restrict__ row_beg, int* total,
        const float* __restrict__ Ws, const float* __restrict__ Wd,
        unsigned short* __restrict__ WtL,
        const float* __restrict__ x, const float* __restrict__ Win,
        const float* __restrict__ bin, unsigned short* __restrict__ hB) {
    const int PB = (NPAIR + 255) / 256;   // 98
    int blk = blockIdx.x, tid = threadIdx.x;
    if (blk < PB) {
        int p = blk * 256 + tid;
        unsigned run = 0;
        if (p < NPAIR) {
            size_t idx = p;
            // r11: unroll 16 (was 4) — the walk is a data-independent address
            // stream; 16 loads in flight cuts the 98-deep latency chain ~4x.
            #pragma unroll 16
            for (int b = 0; b < HB; ++b, idx += NPAIR) {
                unsigned c = cntmat[idx];
                cntmat[idx] = run;          // exclusive prefix for (block b, pair p)
                run += c;
            }
        }
        int c0 = (int)(run & 0xffffu), c1 = (int)(run >> 16);
        int lane = tid & 63;
        int len = (p < NPAIR) ? (c0 + c1 + 2) : 0;   // both nodes + 2 self loops
        int pscan = len;
        #pragma unroll
        for (int off = 1; off < 64; off <<= 1) {
            int t = __shfl_up(pscan, off);
            if (lane >= off) pscan += t;
        }
        int tot = __shfl(pscan, 63);
        int base = 0;
        if (lane == 63) base = atomicAdd(total, tot);
        base = __shfl(base, 63);
        if (p < NPAIR) {
            int rb = base + pscan - len;
            counts[2 * p] = c0;
            counts[2 * p + 1] = c1;
            row_beg[2 * p] = rb;
            row_beg[2 * p + 1] = rb + c0 + 1;
        }
        return;
    }
    int w = tid >> 6, l = tid & 63;
    int m = l & 15, q = l >> 4;
    if (blk < PB + 384) {
        // --- WtL bf16 transpose-convert (3 layers x [256 cols][128 k]) ---
        int e = (blk - PB) * 256 + tid;  // 0..98303
        int ll = e >> 15;
        int r = e & 32767;
        int colc = r >> 7;
        int k = r & 127;
        float v = (colc < 128) ? Ws[ll * 16384 + k * 128 + colc]
                               : Wd[ll * 16384 + k * 128 + (colc - 128)];
        WtL[ll * 32768 + colc * 128 + k] = f2bf(v);
        return;
    }
    // --- in_proj MFMA: x[N,64] @ W_in[64,128] + b -> hB bf16 (W_in converted inline) ---
    int blk0 = blk - PB - 384;           // 0..511
    short8 B[2][2];
    #pragma unroll
    for (int ct = 0; ct < 2; ++ct) {
        int colw = w * 32 + ct * 16 + m;
        #pragma unroll
        for (int kt = 0; kt < 2; ++kt) {
            short8 a;
            #pragma unroll
            for (int jj = 0; jj < 8; ++jj)
                a[jj] = (short)f2bf(Win[(kt * 32 + q * 8 + jj) * 128 + colw]);
            B[ct][kt] = a;
        }
    }
    float bias[2];
    #pragma unroll
    for (int ct = 0; ct < 2; ++ct) bias[ct] = bin[w * 32 + ct * 16 + m];
    for (int rg = blk0; rg < NN / 16; rg += 512) {
        int row0 = rg * 16;
        const float* ap = x + (size_t)(row0 + m) * 64 + q * 8;
        short8 A[2];
        #pragma unroll
        for (int kt = 0; kt < 2; ++kt) {
            float4 f0 = *(const float4*)(ap + kt * 32);
            float4 f1 = *(const float4*)(ap + kt * 32 + 4);
            short8 a;
            a[0] = (short)f2bf(f0.x); a[1] = (short)f2bf(f0.y);
            a[2] = (short)f2bf(f0.z); a[3] = (short)f2bf(f0.w);
            a[4] = (short)f2bf(f1.x); a[5] = (short)f2bf(f1.y);
            a[6] = (short)f2bf(f1.z); a[7] = (short)f2bf(f1.w);
            A[kt] = a;
        }
        f32x4 acc[2];
        #pragma unroll
        for (int ct = 0; ct < 2; ++ct) acc[ct] = (f32x4){0.f, 0.f, 0.f, 0.f};
        #pragma unroll
        for (int kt = 0; kt < 2; ++kt)
            #pragma unroll
            for (int ct = 0; ct < 2; ++ct)
                acc[ct] = __builtin_amdgcn_mfma_f32_16x16x32_bf16(A[kt], B[ct][kt], acc[ct], 0, 0, 0);
        #pragma unroll
        for (int ct = 0; ct < 2; ++ct) {
            int colw = w * 32 + ct * 16 + m;
            #pragma unroll
            for (int i = 0; i < 4; ++i) {
                int row = row0 + q * 4 + i;
                hB[(size_t)row * 128 + colw] = f2bf(acc[ct][i] + bias[ct]);
            }
        }
    }
}

// ---------------- dual GEMM body (used by scatter_dual + standalone) ----------------
__device__ __forceinline__ void dual_body(const unsigned short* __restrict__ hB,
                                          const unsigned short* __restrict__ Wt,
                                          const float* __restrict__ bs,
                                          const float* __restrict__ bd,
                                          unsigned short* __restrict__ fsB,
                                          unsigned short* __restrict__ fdB,
                                          unsigned short* Atile, int t0, int tstride) {
    int tid = threadIdx.x;
    int w = tid >> 6, l = tid & 63;
    int m = l & 15, q = l >> 4;
    short8 B[4][4];
    #pragma unroll
    for (int ct = 0; ct < 4; ++ct) {
        int colw = w * 64 + ct * 16 + m;
        const unsigned short* wp = Wt + colw * 128 + q * 8;
        #pragma unroll
        for (int kt = 0; kt < 4; ++kt) B[ct][kt] = *(const short8*)(wp + kt * 32);
    }
    const float* bptr = (w < 2) ? bs : bd;
    unsigned short* OUT = (w < 2) ? fsB : fdB;
    int ocb = (w * 64) & 127;
    float bias[4];
    #pragma unroll
    for (int ct = 0; ct < 4; ++ct) bias[ct] = bptr[ocb + ct * 16 + m];

    const int NT = (NN + 63) / 64;   // 782 tiles
    for (int t = t0; t < NT; t += tstride) {
        int row0 = t * 64;
        const char* gsrc = (const char*)(hB + (size_t)row0 * 128);
        #pragma unroll
        for (int c = 0; c < 4; ++c) {
            int off = c * 4096 + tid * 16;
            __builtin_amdgcn_global_load_lds((const GLOBAL_AS void*)(gsrc + off),
                                             (LDS_AS void*)((char*)Atile + off), 16, 0, 0);
        }
        __syncthreads();
        #pragma unroll
        for (int rg = 0; rg < 4; ++rg) {
            const unsigned short* ap = Atile + (rg * 16 + m) * 128 + q * 8;
            short8 A[4];
            #pragma unroll
            for (int kt = 0; kt < 4; ++kt) A[kt] = *(const short8*)(ap + kt * 32);
            f32x4 acc[4];
            #pragma unroll
            for (int ct = 0; ct < 4; ++ct) acc[ct] = (f32x4){0.f, 0.f, 0.f, 0.f};
            #pragma unroll
            for (int kt = 0; kt < 4; ++kt)
                #pragma unroll
                for (int ct = 0; ct < 4; ++ct)
                    acc[ct] = __builtin_amdgcn_mfma_f32_16x16x32_bf16(A[kt], B[ct][kt], acc[ct], 0, 0, 0);
            #pragma unroll
            for (int ct = 0; ct < 4; ++ct) {
                int colw = ocb + ct * 16 + m;
                #pragma unroll
                for (int i = 0; i < 4; ++i) {
                    int row = row0 + rg * 16 + q * 4 + i;
                    if (row < NN) OUT[(size_t)row * 128 + colw] = f2bf(acc[ct][i] + bias[ct]);
                }
            }
        }
        __syncthreads();
    }
}

// fused: layer-0 dual GEMM | CSR scatter. Dual tiles get blockIdx 0..NT-1 so the
// long-pole GEMM blocks dispatch FIRST; the ~3320 short scatter blocks backfill.
__global__ __launch_bounds__(256, 4) void scatter_dual_kernel(
        const int* __restrict__ src, const int* __restrict__ dst,
        const int* __restrict__ rank, const int* __restrict__ row_beg,
        const int* __restrict__ counts, const unsigned* __restrict__ cntmat,
        int* __restrict__ col, int E, int n,
        const unsigned short* __restrict__ hB, const unsigned short* __restrict__ Wt,
        const float* __restrict__ bs, const float* __restrict__ bd,
        unsigned short* __restrict__ fsB, unsigned short* __restrict__ fdB) {
    __shared__ unsigned short Atile[64 * 128];   // 16 KB (dual branch only)
    const int NT = (NN + 63) / 64;
    if ((int)blockIdx.x < NT) {
        dual_body(hB, Wt, bs, bd, fsB, fdB, Atile, blockIdx.x, NT);
        return;
    }
    int i = (blockIdx.x - NT) * 256 + threadIdx.x;
    if (i >= E + n) return;
    if (i < E) {
        int d = dst[i];
        int b = i >> CSH;
        unsigned pk = cntmat[(size_t)b * NPAIR + (d >> 1)];
        int off = (int)((pk >> ((unsigned)(d & 1) << 4)) & 0xffffu);
        col[row_beg[d] + off + rank[i]] = src[i];
    } else {
        int v = i - E;
        col[row_beg[v] + counts[v]] = v;
    }
}

// standalone dual (layers 1,2)
__global__ __launch_bounds__(256, 4) void dual_gemm_mfma(const unsigned short* __restrict__ hB,
                                                         const unsigned short* __restrict__ Wt,
                                                         const float* __restrict__ bs,
                                                         const float* __restrict__ bd,
                                                         unsigned short* __restrict__ fsB,
                                                         unsigned short* __restrict__ fdB) {
    __shared__ unsigned short Atile[64 * 128];
    dual_body(hB, Wt, bs, bd, fsB, fdB, Atile, blockIdx.x, gridDim.x);
}

// ---------------- fused gather attention + residual + LN + relu ----------------
// 2 dst nodes/wave, 4 feats/lane, x4 edge ILP, ONE node-pair per wave then exit.
// Lessons locked in: r1 persistent-loop -14%; r6 mid-kernel barrier -2x; r8 x8
// ILP -13%; r9/r10 template-split so only LAST carries the mean-partial epilogue
// (mid layers back at VGPR 40 / LDS 0; r10 top-5 = LAST only, mids below cutoff).
template <bool LAST>
__global__ __launch_bounds__(256) void agg_ln_kernel(const unsigned short* __restrict__ h_in,
                                                     const unsigned short* __restrict__ fsB,
                                                     const unsigned short* __restrict__ fdB,
                                                     const int* __restrict__ row_beg,
                                                     const int* __restrict__ counts,
                                                     const int* __restrict__ col,
                                                     const float* __restrict__ attn,
                                                     const float* __restrict__ ln_g,
                                                     const float* __restrict__ ln_b,
                                                     unsigned short* __restrict__ hb_out,
                                                     float* __restrict__ hf_out,
                                                     float* __restrict__ partials, int n) {
    int gwave = (blockIdx.x * blockDim.x + threadIdx.x) >> 6;
    int wid = threadIdx.x >> 6;
    int lane = threadIdx.x & 63;
    int half = lane >> 5;
    int sub = lane & 31;
    int node = gwave * 2 + half;
    if (node >= n) return;           // never taken at N=50000 (grid exact)
    int f0 = 4 * sub;
    unsigned foff = (unsigned)(f0 * 2);          // byte offset within a 256B bf16 row
    const char* fsp = (const char*)fsB;
    float4 fd4 = bfu4(*(const ushort4*)((const char*)fdB + (((unsigned)node << 8) | foff)));
    float4 h4 = bfu4(*(const ushort4*)((const char*)h_in + (((unsigned)node << 8) | foff)));
    const float4 a4 = *(const float4*)(attn + f0);
    float4 a06, a04;
    a06.x = 0.6f * a4.x; a06.y = 0.6f * a4.y; a06.z = 0.6f * a4.z; a06.w = 0.6f * a4.w;
    a04.x = 0.4f * a4.x; a04.y = 0.4f * a4.y; a04.z = 0.4f * a4.z; a04.w = 0.4f * a4.w;
    int beg = row_beg[node], end = beg + counts[node] + 1;

    float z[4];
    float4 acc[4];
    #pragma unroll
    for (int k = 0; k < 4; ++k) {
        z[k] = 0.f;
        acc[k].x = 0.f; acc[k].y = 0.f; acc[k].z = 0.f; acc[k].w = 0.f;
    }

    int j = beg;
    for (; j + 3 < end; j += 4) {
        int s0 = col[j], s1 = col[j + 1], s2 = col[j + 2], s3 = col[j + 3];
        ushort4 u0 = *(const ushort4*)(fsp + (((unsigned)s0 << 8) | foff));
        ushort4 u1 = *(const ushort4*)(fsp + (((unsigned)s1 << 8) | foff));
        ushort4 u2 = *(const ushort4*)(fsp + (((unsigned)s2 << 8) | foff));
        ushort4 u3 = *(const ushort4*)(fsp + (((unsigned)s3 << 8) | foff));
        float4 v0 = bfu4(u0), v1 = bfu4(u1), v2 = bfu4(u2), v3 = bfu4(u3);
        float p0 = edge_logit(v0, fd4, a06, a04);
        float p1 = edge_logit(v1, fd4, a06, a04);
        float p2 = edge_logit(v2, fd4, a06, a04);
        float p3 = edge_logit(v3, fd4, a06, a04);
        #pragma unroll
        for (int off = 1; off <= 4; off <<= 1) {
            p0 += __shfl_xor(p0, off); p1 += __shfl_xor(p1, off);
            p2 += __shfl_xor(p2, off); p3 += __shfl_xor(p3, off);
        }
        float w0 = __expf(p0), w1 = __expf(p1), w2 = __expf(p2), w3 = __expf(p3);
        z[0] += w0; z[1] += w1; z[2] += w2; z[3] += w3;
        acc[0].x += w0 * v0.x; acc[0].y += w0 * v0.y; acc[0].z += w0 * v0.z; acc[0].w += w0 * v0.w;
        acc[1].x += w1 * v1.x; acc[1].y += w1 * v1.y; acc[1].z += w1 * v1.z; acc[1].w += w1 * v1.w;
        acc[2].x += w2 * v2.x; acc[2].y += w2 * v2.y; acc[2].z += w2 * v2.z; acc[2].w += w2 * v2.w;
        acc[3].x += w3 * v3.x; acc[3].y += w3 * v3.y; acc[3].z += w3 * v3.z; acc[3].w += w3 * v3.w;
    }
    for (; j < end; ++j) {
        int s = col[j];
        ushort4 u = *(const ushort4*)(fsp + (((unsigned)s << 8) | foff));
        float4 v = bfu4(u);
        float p = edge_logit(v, fd4, a06, a04);
        p += __shfl_xor(p, 1);
        p += __shfl_xor(p, 2);
        p += __shfl_xor(p, 4);
        float w = __expf(p);
        z[0] += w;
        acc[0].x += w * v.x; acc[0].y += w * v.y; acc[0].z += w * v.z; acc[0].w += w * v.w;
    }
    float zT = (z[0] + z[1]) + (z[2] + z[3]);
    float axT = (acc[0].x + acc[1].x) + (acc[2].x + acc[3].x);
    float ayT = (acc[0].y + acc[1].y) + (acc[2].y + acc[3].y);
    float azT = (acc[0].z + acc[1].z) + (acc[2].z + acc[3].z);
    float awT = (acc[0].w + acc[1].w) + (acc[2].w + acc[3].w);
    float inv = 1.0f / zT;
    float x0 = 2.f * h4.x + axT * inv;  // h + (aggr + h)
    float x1 = 2.f * h4.y + ayT * inv;
    float x2 = 2.f * h4.z + azT * inv;
    float x3 = 2.f * h4.w + awT * inv;
    float s = (x0 + x1) + (x2 + x3);
    #pragma unroll
    for (int off = 1; off <= 16; off <<= 1) s += __shfl_xor(s, off);
    float mean = s * (1.f / 128.f);
    float d0 = x0 - mean, d1 = x1 - mean, d2 = x2 - mean, d3 = x3 - mean;
    float v = (d0 * d0 + d1 * d1) + (d2 * d2 + d3 * d3);
    #pragma unroll
    for (int off = 1; off <= 16; off <<= 1) v += __shfl_xor(v, off);
    float rstd = rsqrtf(v * (1.f / 128.f) + 1e-5f);
    float4 g4 = *(const float4*)(ln_g + f0);
    float4 bb4 = *(const float4*)(ln_b + f0);
    float4 o;
    o.x = fmaxf(d0 * rstd * g4.x + bb4.x, 0.f);
    o.y = fmaxf(d1 * rstd * g4.y + bb4.y, 0.f);
    o.z = fmaxf(d2 * rstd * g4.z + bb4.z, 0.f);
    o.w = fmaxf(d3 * rstd * g4.w + bb4.w, 0.f);
    if constexpr (LAST) {
        *(float4*)((char*)hf_out + (((unsigned)node << 9) | (unsigned)(f0 * 4))) = o;
        // fused graph-mean partial: sum this block's 8 nodes. Cross-half add first
        // (lane^32 pairs the wave's two nodes), then per-wave LDS row, one barrier,
        // 128 threads emit the block partial. No atomics, no in-loop barriers.
        __shared__ float part[4][128];   // 2 KB, LAST instantiation only
        float4 t = o;
        t.x += __shfl_xor(t.x, 32);
        t.y += __shfl_xor(t.y, 32);
        t.z += __shfl_xor(t.z, 32);
        t.w += __shfl_xor(t.w, 32);
        if (half == 0) *(float4*)(&part[wid][f0]) = t;
        __syncthreads();
        int tt = threadIdx.x;
        if (tt < 128) {
            partials[(size_t)blockIdx.x * 128 + tt] =
                (part[0][tt] + part[1][tt]) + (part[2][tt] + part[3][tt]);
        }
    } else {
        ushort4 ob;
        ob.x = f2bf(o.x); ob.y = f2bf(o.y); ob.z = f2bf(o.z); ob.w = f2bf(o.w);
        *(ushort4*)((char*)hb_out + (((unsigned)node << 8) | foff)) = ob;
    }
}

// ---------------- graph mean finish: 6250 partials -> 256 -> 1 (r7 lesson: a
// single-block reduction of 3.2MB runs at 1-CU bandwidth = 223us; keep 2 stages) ----
__global__ __launch_bounds__(128) void mean_r1_kernel(const float* __restrict__ partials,
                                                      float* __restrict__ partials2, int nb) {
    int c = threadIdx.x;
    float acc = 0.f;
    for (int r = blockIdx.x; r < nb; r += gridDim.x)
        acc += partials[(size_t)r * 128 + c];
    partials2[blockIdx.x * 128 + c] = acc;
}

__global__ __launch_bounds__(1024) void mean2_kernel(const float* __restrict__ partials,
                                                     float* __restrict__ out, int nb, int n) {
    __shared__ float smem[8][128];
    int c = threadIdx.x & 127;
    int g = threadIdx.x >> 7;  // 0..7
    float acc = 0.f;
    for (int r = g; r < nb; r += 8)
        acc += partials[r * 128 + c];
    smem[g][c] = acc;
    __syncthreads();
    if (threadIdx.x < 128) {
        float s = 0.f;
        #pragma unroll
        for (int k = 0; k < 8; ++k) s += smem[k][c];
        out[c] = s * (1.f / n);
    }
}

extern "C" void kernel_launch(void* const* d_in, const int* in_sizes, int n_in,
                              void* d_out, int out_size, void* d_ws, size_t ws_size,
                              hipStream_t stream) {
    const float* node_feats = (const float*)d_in[0];
    const int* src = (const int*)d_in[1];
    const int* dst = (const int*)d_in[2];
    const float* W_in = (const float*)d_in[3];
    const float* b_in = (const float*)d_in[4];
    const float* W_src = (const float*)d_in[5];
    const float* b_src = (const float*)d_in[6];
    const float* W_dst = (const float*)d_in[7];
    const float* b_dst = (const float*)d_in[8];
    const float* attn = (const float*)d_in[9];
    const float* ln_g = (const float*)d_in[10];
    const float* ln_b = (const float*)d_in[11];
    float* out = (float*)d_out;

    const int N = NN;
    const int E = in_sizes[1];
    const int HB = (E + CHUNK - 1) >> CSH;   // 98 hist blocks @ E=800K

    // workspace layout
    unsigned short* fsB = (unsigned short*)d_ws;      // N*128 bf16
    unsigned short* fdB = fsB + (size_t)N * 128;      // N*128 bf16
    unsigned short* hB = fdB + (size_t)N * 128;       // N*128 bf16
    unsigned short* WtL = hB + (size_t)N * 128;       // 3*256*128 bf16
    unsigned short* WtIn = WtL + 3 * 32768;           // 128*64 bf16 (unused, layout kept)
    int* counts = (int*)(WtIn + 8192);                // N
    int* total = counts + N;                          // 1 (zeroed in hist)
    int* row_beg = total + 1;                         // N
    int* rankb = row_beg + N;                         // E
    int* colb = rankb + E;                            // E+N
    unsigned* cntmat = (unsigned*)(colb + (E + N));   // HB*NPAIR u32 (~9.8MB)
    float* partials = (float*)(cntmat + (size_t)HB * NPAIR);  // 6250*128 f32 (3.2MB)
    float* partials2 = partials + (size_t)6250 * 128;         // 256*128 f32

    const int NT = (N + 63) / 64;   // 782 dual tiles
    const int AB = (N + 7) / 8;     // 6250 agg blocks (N % 8 == 0: every wave full)

    // --- pass 1: block-local LDS hist (no device atomics; zeroes `total`) ---
    hist_kernel<<<HB, 256, 0, stream>>>(dst, cntmat, rankb, total, E);

    // --- pass 2: block-prefix + alloc | WtL convert | in_proj ---
    const int PB = (NPAIR + 255) / 256;   // 98
    prep2_kernel<<<PB + 384 + 512, 256, 0, stream>>>(cntmat, HB, counts, row_beg, total,
                                                     W_src, W_dst, WtL,
                                                     node_feats, W_in, b_in, hB);

    // --- pass 3: layer-0 dual GEMM (blocks first) | scatter ---
    int SB = (E + N + 255) / 256;
    scatter_dual_kernel<<<NT + SB, 256, 0, stream>>>(src, dst, rankb, row_beg,
                                                     counts, cntmat, colb, E, N,
                                                     hB, WtL, b_src, b_dst, fsB, fdB);

    // --- 3 GATv2 layers ---
    for (int l = 0; l < 3; ++l) {
        if (l > 0)
            dual_gemm_mfma<<<NT, 256, 0, stream>>>(hB, WtL + (size_t)l * 32768,
                                                   b_src + l * 128, b_dst + l * 128,
                                                   fsB, fdB);
        if (l < 2)
            agg_ln_kernel<false><<<AB, 256, 0, stream>>>(hB, fsB, fdB, row_beg, counts, colb,
                                                         attn + l * 128, ln_g + l * 128,
                                                         ln_b + l * 128, hB, nullptr,
                                                         partials, N);
        else
            agg_ln_kernel<true><<<AB, 256, 0, stream>>>(hB, fsB, fdB, row_beg, counts, colb,
                                                        attn + l * 128, ln_g + l * 128,
                                                        ln_b + l * 128, nullptr, out + 128,
                                                        partials, N);
    }

    // --- graph mean finish into out[0:128] (two-stage over block partials) ---
    mean_r1_kernel<<<256, 128, 0, stream>>>(partials, partials2, AB);
    mean2_kernel<<<1, 1024, 0, stream>>>(partials2, out, 256, N);
}